// Round 7
// baseline (7752.058 us; speedup 1.0000x reference)
//
#include <hip/hip_runtime.h>

#define NRES 256
#define P_TOT (NRES*NRES)
#define P64   (P_TOT*64)

#define FMA16(A4, B4, ACC) do { \
  ACC[0][0] += A4.x*B4.x; ACC[0][1] += A4.x*B4.y; ACC[0][2] += A4.x*B4.z; ACC[0][3] += A4.x*B4.w; \
  ACC[1][0] += A4.y*B4.x; ACC[1][1] += A4.y*B4.y; ACC[1][2] += A4.y*B4.z; ACC[1][3] += A4.y*B4.w; \
  ACC[2][0] += A4.z*B4.x; ACC[2][1] += A4.z*B4.y; ACC[2][2] += A4.z*B4.z; ACC[2][3] += A4.z*B4.w; \
  ACC[3][0] += A4.w*B4.x; ACC[3][1] += A4.w*B4.y; ACC[3][2] += A4.w*B4.z; ACC[3][3] += A4.w*B4.w; \
} while (0)

__device__ __forceinline__ float sgm(float x) { return 1.0f / (1.0f + __expf(-x)); }

// ---------------------------------------------------------------------------
// Backbone frames: rot (pre-swapaxes) + trans, 12 floats per residue.
// ---------------------------------------------------------------------------
__global__ void k_transform(const float* __restrict__ pos, float* __restrict__ rt) {
  int i = threadIdx.x;
  if (i >= NRES) return;
  const float* p = pos + i*37*3;
  float nx = p[0], ny = p[1], nz = p[2];
  float cax = p[3], cay = p[4], caz = p[5];
  float ccx = p[6], ccy = p[7], ccz = p[8];
  float c0x = ccx - cax, c0y = ccy - cay, c0z = ccz - caz;
  float n0x = nx - cax, n0y = ny - cay, n0z = nz - caz;
  float norm1 = sqrtf(1e-20f + c0x*c0x + c0y*c0y);
  float s1 = -c0y / norm1, c1 = c0x / norm1;
  float norm2 = sqrtf(1e-20f + c0x*c0x + c0y*c0y + c0z*c0z);
  float s2 = c0z / norm2, c2 = sqrtf(c0x*c0x + c0y*c0y) / norm2;
  float r00 = c2*c1,   r01 = -c2*s1,  r02 = s2;
  float r10 = s1,      r11 = c1,      r12 = 0.f;
  float r20 = -s2*c1,  r21 = s2*s1,   r22 = c2;
  float py = r10*n0x + r11*n0y + r12*n0z;
  float pz = r20*n0x + r21*n0y + r22*n0z;
  float norm3 = sqrtf(1e-20f + py*py + pz*pz);
  float sn = -pz / norm3, cn = py / norm3;
  float* o = rt + i*12;
  o[0] = r00; o[1] = r01; o[2] = r02;
  o[3] = cn*r10 - sn*r20; o[4] = cn*r11 - sn*r21; o[5] = cn*r12 - sn*r22;
  o[6] = sn*r10 + cn*r20; o[7] = sn*r11 + cn*r21; o[8] = sn*r12 + cn*r22;
  o[9] = cax; o[10] = cay; o[11] = caz;
}

// ---------------------------------------------------------------------------
// Features -> embedding. feat = 8 nonzero rows of emb_w (one-hots collapse).
// Phase 1: thread j computes coefficients -> LDS. Phase 2: lane = channel,
// wave = j-subgroup -> coalesced 256B stores (fixes 16x write amplification).
// ---------------------------------------------------------------------------
__global__ __launch_bounds__(256) void k_feat_embed(
    const int* __restrict__ aatype, const float* __restrict__ bmask,
    const float* __restrict__ beta, const float* __restrict__ amask,
    const float* __restrict__ rt, const float* __restrict__ emb_w,
    const float* __restrict__ emb_b, float* __restrict__ act) {
  __shared__ float ew[88][68];
  __shared__ float eb[64];
  __shared__ float cf[5][256];   // bm2, ux, uy, uz, bb2 per j
  __shared__ int   ci[2][256];   // bin, rj per j
  int t = threadIdx.x;
  for (int idx = t; idx < 88*64; idx += 256) ew[idx >> 6][idx & 63] = emb_w[idx];
  if (t < 64) eb[t] = emb_b[t];
  int i = blockIdx.x;
  {
    int j = t;
    float bm2 = bmask[i] * bmask[j];
    float dx = beta[i*3+0] - beta[j*3+0];
    float dy = beta[i*3+1] - beta[j*3+1];
    float dz = beta[i*3+2] - beta[j*3+2];
    float d2 = dx*dx + dy*dy + dz*dz;
    int bin = -1;
    for (int k = 0; k < 39; k++) {
      float lk = 3.25f + 1.25f * (float)k;
      float lo = lk * lk;
      float up = (k == 38) ? 1e8f : (lk + 1.25f) * (lk + 1.25f);
      if (d2 > lo && d2 < up) bin = k;
    }
    int aaj = aatype[j];
    float bbi = amask[i*37+0] * amask[i*37+1] * amask[i*37+2];
    float bbj = amask[j*37+0] * amask[j*37+1] * amask[j*37+2];
    float bb2 = bbi * bbj;
    const float* R = rt + i*12;
    float tx = rt[j*12+9]  - R[9];
    float ty = rt[j*12+10] - R[10];
    float tz = rt[j*12+11] - R[11];
    float ax = R[0]*tx + R[1]*ty + R[2]*tz;
    float ay = R[3]*tx + R[4]*ty + R[5]*tz;
    float az = R[6]*tx + R[7]*ty + R[8]*tz;
    float f = (1.0f / sqrtf(1e-6f + ax*ax + ay*ay + az*az)) * bb2;
    cf[0][j] = bm2;
    cf[1][j] = ax*f; cf[2][j] = ay*f; cf[3][j] = az*f;
    cf[4][j] = bb2;
    ci[0][j] = bin;
    ci[1][j] = 40 + aaj;
  }
  __syncthreads();
  int ri = 62 + aatype[i];
  int c = t & 63, js = t >> 6;
  for (int jj = 0; jj < 64; jj++) {
    int j = jj*4 + js;
    float bm2 = cf[0][j], ux = cf[1][j], uy = cf[2][j], uz = cf[3][j], bb2 = cf[4][j];
    int bin = ci[0][j], rj = ci[1][j];
    float a = (bin >= 0 ? ew[bin][c] : 0.f) + bm2*ew[39][c] + ew[rj][c] + ew[ri][c]
            + ux*ew[84][c] + uy*ew[85][c] + uz*ew[86][c] + bb2*ew[87][c];
    act[((size_t)i*NRES + j)*64 + c] = bb2*a + eb[c];
  }
}

// ---------------------------------------------------------------------------
// LayerNorm over last dim (64). One wave per row, lane = channel.
// ---------------------------------------------------------------------------
__global__ __launch_bounds__(256) void k_ln(const float* __restrict__ src, float* __restrict__ dst,
                                            const float* __restrict__ s, const float* __restrict__ b,
                                            int transpose) {
  int lane = threadIdx.x & 63;
  int wave = blockIdx.x * (blockDim.x >> 6) + (threadIdx.x >> 6);
  int nw = gridDim.x * (blockDim.x >> 6);
  float sc = s[lane], bc = b[lane];
  for (int p = wave; p < P_TOT; p += nw) {
    int sp = transpose ? ((p & 255)*NRES + (p >> 8)) : p;
    float x = src[sp*64 + lane];
    float mu = x;
    for (int o = 1; o < 64; o <<= 1) mu += __shfl_xor(mu, o);
    mu *= (1.0f/64.0f);
    float d = x - mu;
    float v = d*d;
    for (int o = 1; o < 64; o <<= 1) v += __shfl_xor(v, o);
    v *= (1.0f/64.0f);
    dst[p*64 + lane] = d * (1.0f / sqrtf(v + 1e-5f)) * sc + bc;
  }
}

// ---------------------------------------------------------------------------
// nbT[h][k][q] = sum_c xln[(q,k),c] * f2d[c,h]. Coalesced writes (lane=q).
// ---------------------------------------------------------------------------
__global__ __launch_bounds__(256) void k_nb(
    const float* __restrict__ xln, const float* __restrict__ f2d,
    float* __restrict__ nbT) {
  __shared__ float fs[64][4];
  int t = threadIdx.x;
  fs[t >> 2][t & 3] = f2d[t];
  __syncthreads();
  int k = blockIdx.x, q = t;
  const float4* xr = (const float4*)(xln + ((size_t)q*NRES + k)*64);
  float a0 = 0, a1 = 0, a2 = 0, a3 = 0;
  #pragma unroll
  for (int c4 = 0; c4 < 16; c4++) {
    float4 xv = xr[c4];
    int c = c4*4;
    a0 += xv.x*fs[c][0] + xv.y*fs[c+1][0] + xv.z*fs[c+2][0] + xv.w*fs[c+3][0];
    a1 += xv.x*fs[c][1] + xv.y*fs[c+1][1] + xv.z*fs[c+2][1] + xv.w*fs[c+3][1];
    a2 += xv.x*fs[c][2] + xv.y*fs[c+1][2] + xv.z*fs[c+2][2] + xv.w*fs[c+3][2];
    a3 += xv.x*fs[c][3] + xv.y*fs[c+1][3] + xv.z*fs[c+2][3] + xv.w*fs[c+3][3];
  }
  int base = k*NRES + q;
  nbT[base]          = a0;
  nbT[65536  + base] = a1;
  nbT[131072 + base] = a2;
  nbT[196608 + base] = a3;
}

// ---------------------------------------------------------------------------
// Fused q/k/v/gate projections: ONE pass over X (staged once), loop the 4
// weight sets in-block. ti=t>>4 rows / tj=t&15 cols -> coalesced stores.
// ---------------------------------------------------------------------------
__global__ __launch_bounds__(256, 4) void k_proj(
    const float* __restrict__ X,
    const float* __restrict__ QW, const float* __restrict__ KW,
    const float* __restrict__ VW, const float* __restrict__ GW,
    const float* __restrict__ GBb,
    float* __restrict__ Yq, float* __restrict__ Yk,
    float* __restrict__ Yv, float* __restrict__ Yg) {
  __shared__ float Xs[64][68];
  __shared__ float Ws[64][68];
  int t = threadIdx.x, ti = t >> 4, tj = t & 15;
  int p0 = blockIdx.x * 64;
  #pragma unroll
  for (int e = 0; e < 16; e++) {
    int idx = t + e*256;
    int r = idx >> 6, c = idx & 63;
    Xs[c][r] = X[(size_t)(p0 + r)*64 + c];
  }
  for (int sel = 0; sel < 4; sel++) {
    const float* W = sel == 0 ? QW : sel == 1 ? KW : sel == 2 ? VW : GW;
    float* Y = sel == 0 ? Yq : sel == 1 ? Yk : sel == 2 ? Yv : Yg;
    #pragma unroll
    for (int e = 0; e < 16; e++) {
      int idx = t + e*256;
      Ws[idx >> 6][idx & 63] = W[idx];
    }
    __syncthreads();
    float acc[4][4] = {{0}};
    #pragma unroll
    for (int kk = 0; kk < 64; kk++) {
      float4 a = *((const float4*)&Xs[kk][ti*4]);
      float4 b = *((const float4*)&Ws[kk][tj*4]);
      FMA16(a, b, acc);
    }
    __syncthreads();   // all waves done with Ws before next restage
    float gb4[4] = {0,0,0,0};
    if (sel == 3) {
      #pragma unroll
      for (int v = 0; v < 4; v++) gb4[v] = GBb[tj*4 + v];
    }
    float scale = (sel == 0) ? 0.25f : 1.0f;
    #pragma unroll
    for (int u = 0; u < 4; u++) {
      int p = p0 + ti*4 + u;
      float4 o;
      if (sel == 3) {
        o.x = sgm(acc[u][0] + gb4[0]); o.y = sgm(acc[u][1] + gb4[1]);
        o.z = sgm(acc[u][2] + gb4[2]); o.w = sgm(acc[u][3] + gb4[3]);
      } else {
        o.x = acc[u][0]*scale; o.y = acc[u][1]*scale;
        o.z = acc[u][2]*scale; o.w = acc[u][3]*scale;
      }
      *((float4*)&Y[(size_t)p*64 + tj*4]) = o;
    }
  }
}

// ---------------------------------------------------------------------------
// Flash attention per (b,h), no max-tracking (logits analytically bounded).
// 128 threads, 2 queries per thread. Writes (wa*gate) in-place into Q.
// ---------------------------------------------------------------------------
__global__ __launch_bounds__(128) void k_attn(
    float* __restrict__ Q, const float* __restrict__ Kb, const float* __restrict__ Vb,
    const float* __restrict__ G, const float* __restrict__ nbT,
    const float* __restrict__ mask, int ending) {
  __shared__ float ks[256][16];
  __shared__ float vs[256][16];
  __shared__ float bs[256];
  int b = blockIdx.x, h = blockIdx.y;
  int t = threadIdx.x;
  #pragma unroll
  for (int s = 0; s < 2; s++) {
    int k = t + s*128;
    const float4* kr = (const float4*)(Kb + ((size_t)b*NRES + k)*64 + h*16);
    const float4* vr = (const float4*)(Vb + ((size_t)b*NRES + k)*64 + h*16);
    float4* kd = (float4*)ks[k];
    float4* vd = (float4*)vs[k];
    #pragma unroll
    for (int d4 = 0; d4 < 4; d4++) { kd[d4] = kr[d4]; vd[d4] = vr[d4]; }
    float m = ending ? mask[k*NRES + b] : mask[b*NRES + k];
    bs[k] = 1e9f * (m - 1.0f);
  }
  __syncthreads();
  int q0 = t, q1 = t + 128;
  float* qr0 = Q + ((size_t)b*NRES + q0)*64 + h*16;
  float* qr1 = Q + ((size_t)b*NRES + q1)*64 + h*16;
  float4 qv0[4], qv1[4];
  #pragma unroll
  for (int d4 = 0; d4 < 4; d4++) { qv0[d4] = ((const float4*)qr0)[d4]; qv1[d4] = ((const float4*)qr1)[d4]; }
  const float* nbr = nbT + h*65536;
  float l0 = 0.0f, l1 = 0.0f;
  float acc0[16], acc1[16];
  #pragma unroll
  for (int d = 0; d < 16; d++) { acc0[d] = 0.0f; acc1[d] = 0.0f; }
  #pragma unroll 2
  for (int k = 0; k < 256; k++) {
    float dot0 = 0.0f, dot1 = 0.0f;
    #pragma unroll
    for (int d4 = 0; d4 < 4; d4++) {
      float4 kv = *((const float4*)&ks[k][d4*4]);
      dot0 += qv0[d4].x*kv.x + qv0[d4].y*kv.y + qv0[d4].z*kv.z + qv0[d4].w*kv.w;
      dot1 += qv1[d4].x*kv.x + qv1[d4].y*kv.y + qv1[d4].z*kv.z + qv1[d4].w*kv.w;
    }
    float bk = bs[k];
    float p0 = __expf(dot0 + bk + nbr[(k << 8) + q0]);
    float p1 = __expf(dot1 + bk + nbr[(k << 8) + q1]);
    l0 += p0; l1 += p1;
    #pragma unroll
    for (int d4 = 0; d4 < 4; d4++) {
      float4 vv = *((const float4*)&vs[k][d4*4]);
      acc0[d4*4+0] += p0*vv.x; acc0[d4*4+1] += p0*vv.y;
      acc0[d4*4+2] += p0*vv.z; acc0[d4*4+3] += p0*vv.w;
      acc1[d4*4+0] += p1*vv.x; acc1[d4*4+1] += p1*vv.y;
      acc1[d4*4+2] += p1*vv.z; acc1[d4*4+3] += p1*vv.w;
    }
  }
  float inv0 = 1.0f / l0, inv1 = 1.0f / l1;
  const float4* gr0 = (const float4*)(G + ((size_t)b*NRES + q0)*64 + h*16);
  const float4* gr1 = (const float4*)(G + ((size_t)b*NRES + q1)*64 + h*16);
  #pragma unroll
  for (int d4 = 0; d4 < 4; d4++) {
    float4 gv0 = gr0[d4], gv1 = gr1[d4];
    float4 o0, o1;
    o0.x = acc0[d4*4+0]*inv0*gv0.x; o0.y = acc0[d4*4+1]*inv0*gv0.y;
    o0.z = acc0[d4*4+2]*inv0*gv0.z; o0.w = acc0[d4*4+3]*inv0*gv0.w;
    o1.x = acc1[d4*4+0]*inv1*gv1.x; o1.y = acc1[d4*4+1]*inv1*gv1.y;
    o1.z = acc1[d4*4+2]*inv1*gv1.z; o1.w = acc1[d4*4+3]*inv1*gv1.w;
    ((float4*)qr0)[d4] = o0;
    ((float4*)qr1)[d4] = o1;
  }
}

// ---------------------------------------------------------------------------
// Generic tiled GEMM, coalesced-store microtile (ti=t>>4 rows, tj=t&15 cols).
// ---------------------------------------------------------------------------
template<int ACT, bool RESID, bool TRANSRES>
__global__ __launch_bounds__(256, 4) void k_gemm(
    const float* __restrict__ X, int K, int N,
    const float* __restrict__ W, const float* __restrict__ B,
    float* __restrict__ Y) {
  __shared__ float Xs[64][68];
  __shared__ float Ws[64][68];
  int t = threadIdx.x, ti = t >> 4, tj = t & 15;
  int p0 = blockIdx.x * 64, n0 = blockIdx.y * 64;
  float acc[4][4] = {{0}};
  for (int kc = 0; kc < K; kc += 64) {
    #pragma unroll
    for (int e = 0; e < 16; e++) {
      int idx = t + e*256;
      int r = idx >> 6, c = idx & 63;
      Xs[c][r] = X[(size_t)(p0 + r)*K + kc + c];
      Ws[r][c] = W[(size_t)(kc + r)*N + n0 + c];
    }
    __syncthreads();
    #pragma unroll
    for (int kk = 0; kk < 64; kk++) {
      float4 a = *((const float4*)&Xs[kk][ti*4]);
      float4 b = *((const float4*)&Ws[kk][tj*4]);
      FMA16(a, b, acc);
    }
    __syncthreads();
  }
  float bv[4] = {0,0,0,0};
  if (B) {
    #pragma unroll
    for (int v = 0; v < 4; v++) bv[v] = B[n0 + tj*4 + v];
  }
  #pragma unroll
  for (int u = 0; u < 4; u++) {
    int p = p0 + ti*4 + u;
    float res[4];
    #pragma unroll
    for (int v = 0; v < 4; v++) {
      float val = acc[u][v] + bv[v];
      if (ACT == 1) val = sgm(val);
      if (ACT == 2) val = fmaxf(val, 0.0f);
      res[v] = val;
    }
    if (RESID) {
      int row = TRANSRES ? ((p & 255)*NRES + (p >> 8)) : p;
      float4* yp = (float4*)&Y[(size_t)row*64 + n0 + tj*4];
      float4 old = *yp;
      old.x += res[0]; old.y += res[1]; old.z += res[2]; old.w += res[3];
      *yp = old;
    } else {
      *((float4*)&Y[(size_t)p*N + n0 + tj*4]) = make_float4(res[0], res[1], res[2], res[3]);
    }
  }
}

// ---------------------------------------------------------------------------
// Dual gated projection for triangle-mult, writing in plane layout Y[c][p]
// via LDS retranspose (global stores already coalesced; keep old mapping).
// ---------------------------------------------------------------------------
__global__ __launch_bounds__(256, 4) void k_dual2(
    const float* __restrict__ X,
    const float* __restrict__ PW0, const float* __restrict__ PB0,
    const float* __restrict__ GW0, const float* __restrict__ GB0,
    const float* __restrict__ PW1, const float* __restrict__ PB1,
    const float* __restrict__ GW1, const float* __restrict__ GB1,
    const float* __restrict__ mask,
    float* __restrict__ Y0, float* __restrict__ Y1) {
  __shared__ float Xs[64][68];
  __shared__ float Wp[64][68];
  __shared__ float Wg[64][68];
  int t = threadIdx.x, ti = t & 15, tj = t >> 4;
  int p0 = blockIdx.x * 64, sel = blockIdx.y;
  const float* PW = sel ? PW1 : PW0;
  const float* PB = sel ? PB1 : PB0;
  const float* GW = sel ? GW1 : GW0;
  const float* GB = sel ? GB1 : GB0;
  float* Y = sel ? Y1 : Y0;
  #pragma unroll
  for (int e = 0; e < 16; e++) {
    int idx = t + e*256;
    int r = idx >> 6, c = idx & 63;
    Xs[c][r] = X[(size_t)(p0 + r)*64 + c];
    Wp[r][c] = PW[idx];
    Wg[r][c] = GW[idx];
  }
  __syncthreads();
  float acc1[4][4] = {{0}};
  float acc2[4][4] = {{0}};
  #pragma unroll
  for (int kk = 0; kk < 64; kk++) {
    float4 a  = *((const float4*)&Xs[kk][ti*4]);
    float4 b1 = *((const float4*)&Wp[kk][tj*4]);
    FMA16(a, b1, acc1);
    float4 b2 = *((const float4*)&Wg[kk][tj*4]);
    FMA16(a, b2, acc2);
  }
  __syncthreads();   // done reading Wp; reuse it as retranspose tile [n][r]
  float pb4[4], gb4[4];
  #pragma unroll
  for (int v = 0; v < 4; v++) { pb4[v] = PB[tj*4 + v]; gb4[v] = GB[tj*4 + v]; }
  #pragma unroll
  for (int u = 0; u < 4; u++) {
    int p = p0 + ti*4 + u;
    float mp = mask[p];
    #pragma unroll
    for (int v = 0; v < 4; v++) {
      Wp[tj*4 + v][ti*4 + u] = mp * (acc1[u][v] + pb4[v]) * sgm(acc2[u][v] + gb4[v]);
    }
  }
  __syncthreads();
  #pragma unroll
  for (int e = 0; e < 16; e++) {
    int idx = t + e*256;
    int n = idx >> 6, r = idx & 63;
    Y[(size_t)n*65536 + p0 + r] = Wp[n][r];
  }
}

// ---------------------------------------------------------------------------
// 64 per-channel 256^3 GEMMs. NT: O=A·Bᵀ rows; TN: O=Aᵀ·B (planes [c][p]).
// ---------------------------------------------------------------------------
template<bool TN>
__global__ __launch_bounds__(256, 4) void k_plane_gemm(const float* __restrict__ A,
                                                       const float* __restrict__ B,
                                                       float* __restrict__ O) {
  __shared__ float As[32][68];
  __shared__ float Bs[32][68];
  int c = blockIdx.x, it = blockIdx.y, jt = blockIdx.z;
  const float* Ac = A + (size_t)c*65536;
  const float* Bc = B + (size_t)c*65536;
  int t = threadIdx.x, ti = t >> 4, tj = t & 15;
  float acc[4][4] = {{0}};
  for (int k0 = 0; k0 < 256; k0 += 32) {
    if (TN) {
      #pragma unroll
      for (int e = 0; e < 8; e++) {
        int idx = t + e*256;
        int kk = idx >> 6, r = idx & 63;
        As[kk][r] = Ac[(k0 + kk)*NRES + it*64 + r];
        Bs[kk][r] = Bc[(k0 + kk)*NRES + jt*64 + r];
      }
    } else {
      #pragma unroll
      for (int e = 0; e < 8; e++) {
        int idx = t + e*256;
        int r = idx >> 5, kk = idx & 31;
        As[kk][r] = Ac[(it*64 + r)*NRES + k0 + kk];
        Bs[kk][r] = Bc[(jt*64 + r)*NRES + k0 + kk];
      }
    }
    __syncthreads();
    #pragma unroll
    for (int kk = 0; kk < 32; kk++) {
      float4 a = *((const float4*)&As[kk][ti*4]);
      float4 b = *((const float4*)&Bs[kk][tj*4]);
      FMA16(a, b, acc);
    }
    __syncthreads();
  }
  int ib = it*64 + ti*4, jb = jt*64 + tj*4;
  #pragma unroll
  for (int u = 0; u < 4; u++) {
    *((float4*)&O[(size_t)c*65536 + (ib + u)*NRES + jb]) =
        make_float4(acc[u][0], acc[u][1], acc[u][2], acc[u][3]);
  }
}

// ---------------------------------------------------------------------------
// Tri-mult epilogue as dual GEMM with LN fused into the A-tile load.
// ---------------------------------------------------------------------------
__global__ __launch_bounds__(256, 4) void k_gate(
    const float* __restrict__ OT, const float* __restrict__ X2,
    const float* __restrict__ cs, const float* __restrict__ cb,
    const float* __restrict__ OW, const float* __restrict__ OB,
    const float* __restrict__ GW, const float* __restrict__ GB,
    float* __restrict__ act) {
  __shared__ float Xs[64][68];
  __shared__ float X2s[64][68];
  __shared__ float Wo[64][68];
  __shared__ float Wg[64][68];
  __shared__ float red[4][64];
  __shared__ float mrs[2][64];
  __shared__ float cln[2][64];
  int t = threadIdx.x, ti = t >> 4, tj = t & 15;
  int p0 = blockIdx.x * 64;
  if (t < 64) { cln[0][t] = cs[t]; cln[1][t] = cb[t]; }
  #pragma unroll
  for (int e = 0; e < 16; e++) {
    int idx = t + e*256;
    int rA = idx & 63, cA = idx >> 6;
    Xs[cA][rA]  = OT[(size_t)cA*65536 + p0 + rA];   // lanes walk rA: coalesced
    X2s[rA][cA] = X2[(size_t)(p0 + cA)*64 + rA];    // lanes walk rA (=channel)
    Wo[cA][rA]  = OW[idx];
    Wg[cA][rA]  = GW[idx];
  }
  __syncthreads();
  // LN over channel (first index of Xs) per column r
  int s4 = t >> 6, r = t & 63;
  float p1 = 0.f;
  #pragma unroll
  for (int cc = 0; cc < 16; cc++) p1 += Xs[s4*16 + cc][r];
  red[s4][r] = p1;
  __syncthreads();
  if (t < 64) mrs[0][t] = (red[0][t] + red[1][t] + red[2][t] + red[3][t]) * 0.015625f;
  __syncthreads();
  float mu_ = mrs[0][r];
  float v1 = 0.f;
  #pragma unroll
  for (int cc = 0; cc < 16; cc++) { float d = Xs[s4*16 + cc][r] - mu_; v1 += d*d; }
  red[s4][r] = v1;
  __syncthreads();
  if (t < 64) {
    float v = (red[0][t] + red[1][t] + red[2][t] + red[3][t]) * 0.015625f;
    mrs[1][t] = 1.0f / sqrtf(v + 1e-5f);
  }
  __syncthreads();
  float rs_ = mrs[1][r];
  #pragma unroll
  for (int cc = 0; cc < 16; cc++) {
    int c = s4*16 + cc;
    Xs[c][r] = (Xs[c][r] - mu_) * rs_ * cln[0][c] + cln[1][c];
  }
  __syncthreads();
  float acc1[4][4] = {{0}};
  float acc2[4][4] = {{0}};
  #pragma unroll
  for (int kk = 0; kk < 64; kk++) {
    float4 a  = *((const float4*)&Xs[kk][ti*4]);
    float4 b1 = *((const float4*)&Wo[kk][tj*4]);
    FMA16(a, b1, acc1);
    float4 a2 = *((const float4*)&X2s[kk][ti*4]);
    float4 b2 = *((const float4*)&Wg[kk][tj*4]);
    FMA16(a2, b2, acc2);
  }
  float obv[4], gbv[4];
  #pragma unroll
  for (int v = 0; v < 4; v++) { obv[v] = OB[tj*4 + v]; gbv[v] = GB[tj*4 + v]; }
  #pragma unroll
  for (int u = 0; u < 4; u++) {
    int p = p0 + ti*4 + u;
    float4* yp = (float4*)&act[(size_t)p*64 + tj*4];
    float4 old = *yp;
    old.x += (acc1[u][0] + obv[0]) * sgm(acc2[u][0] + gbv[0]);
    old.y += (acc1[u][1] + obv[1]) * sgm(acc2[u][1] + gbv[1]);
    old.z += (acc1[u][2] + obv[2]) * sgm(acc2[u][2] + gbv[2]);
    old.w += (acc1[u][3] + obv[3]) * sgm(acc2[u][3] + gbv[3]);
    *yp = old;
  }
}

// ---------------------------------------------------------------------------
extern "C" void kernel_launch(void* const* d_in, const int* in_sizes, int n_in,
                              void* d_out, int out_size, void* d_ws, size_t ws_size,
                              hipStream_t stream) {
  const int*   aatype  = (const int*)d_in[1];
  const float* bmask   = (const float*)d_in[2];
  const float* beta    = (const float*)d_in[3];
  const float* apos    = (const float*)d_in[4];
  const float* amask   = (const float*)d_in[5];
  const float* mask2d  = (const float*)d_in[6];
  const float* emb_w   = (const float*)d_in[7];
  const float* emb_b   = (const float*)d_in[8];
  const float* out_ln_s = (const float*)d_in[9];
  const float* out_ln_b = (const float*)d_in[10];
  const float* ta_ln_s = (const float*)d_in[11];
  const float* ta_ln_b = (const float*)d_in[12];
  const float* ta_f2d  = (const float*)d_in[13];
  const float* ta_qw   = (const float*)d_in[14];
  const float* ta_kw   = (const float*)d_in[15];
  const float* ta_vw   = (const float*)d_in[16];
  const float* ta_gw   = (const float*)d_in[17];
  const float* ta_gb   = (const float*)d_in[18];
  const float* ta_ow   = (const float*)d_in[19];
  const float* ta_ob   = (const float*)d_in[20];
  const float* tm_ln_s = (const float*)d_in[21];
  const float* tm_ln_b = (const float*)d_in[22];
  const float* tm_lpw  = (const float*)d_in[23];
  const float* tm_lpb  = (const float*)d_in[24];
  const float* tm_lgw  = (const float*)d_in[25];
  const float* tm_lgb  = (const float*)d_in[26];
  const float* tm_rpw  = (const float*)d_in[27];
  const float* tm_rpb  = (const float*)d_in[28];
  const float* tm_rgw  = (const float*)d_in[29];
  const float* tm_rgb  = (const float*)d_in[30];
  const float* tm_cln_s = (const float*)d_in[31];
  const float* tm_cln_b = (const float*)d_in[32];
  const float* tm_ow   = (const float*)d_in[33];
  const float* tm_ob   = (const float*)d_in[34];
  const float* tm_gw   = (const float*)d_in[35];
  const float* tm_gb   = (const float*)d_in[36];
  const float* tr_ln_s = (const float*)d_in[37];
  const float* tr_ln_b = (const float*)d_in[38];
  const float* tr_w1   = (const float*)d_in[39];
  const float* tr_b1   = (const float*)d_in[40];
  const float* tr_w2   = (const float*)d_in[41];
  const float* tr_b2   = (const float*)d_in[42];

  float* ws  = (float*)d_ws;
  float* rt  = ws;                    // 4096
  float* act = ws + 4096;             // 4 M floats
  float* xln = act + P64;             // 4 M
  float* nbT = xln + P64;             // 256 K
  float* b0  = nbT + 262144;          // 4 M
  float* b1  = b0 + P64;              // 4 M
  float* b2  = b1 + P64;              // 4 M
  float* b3  = (float*)d_out;         // gate / plane scratch; final output

  dim3 blk(256);

  k_transform<<<1, blk, 0, stream>>>(apos, rt);
  k_feat_embed<<<256, blk, 0, stream>>>(aatype, bmask, beta, amask, rt, emb_w, emb_b, act);

  for (int B = 0; B < 2; B++) {
    // ---- triangle attention (starting e=0, ending e=1) ----
    for (int e = 0; e < 2; e++) {
      int bi = B*2 + e;
      k_ln<<<2048, blk, 0, stream>>>(act, xln, ta_ln_s + bi*64, ta_ln_b + bi*64, e);
      k_nb<<<256, blk, 0, stream>>>(xln, ta_f2d + bi*256, nbT);
      k_proj<<<dim3(1024), blk, 0, stream>>>(
          xln, ta_qw + bi*4096, ta_kw + bi*4096, ta_vw + bi*4096, ta_gw + bi*4096,
          ta_gb + bi*64, b0, b1, b2, b3);
      k_attn<<<dim3(256, 4), dim3(128), 0, stream>>>(b0, b1, b2, b3, nbT, mask2d, e);
      if (e == 0)
        k_gemm<0,true,false><<<dim3(1024, 1), blk, 0, stream>>>(
            b0, 64, 64, ta_ow + bi*4096, ta_ob + bi*64, act);
      else
        k_gemm<0,true,true><<<dim3(1024, 1), blk, 0, stream>>>(
            b0, 64, 64, ta_ow + bi*4096, ta_ob + bi*64, act);
    }
    // ---- triangle multiplication (outgoing e=0, incoming e=1) ----
    for (int e = 0; e < 2; e++) {
      int bi = B*2 + e;
      k_ln<<<2048, blk, 0, stream>>>(act, xln, tm_ln_s + bi*64, tm_ln_b + bi*64, 0);
      k_dual2<<<dim3(1024, 2), blk, 0, stream>>>(
          xln, tm_lpw + bi*4096, tm_lpb + bi*64, tm_lgw + bi*4096, tm_lgb + bi*64,
          tm_rpw + bi*4096, tm_rpb + bi*64, tm_rgw + bi*4096, tm_rgb + bi*64,
          mask2d, b1, b2);
      if (e == 0)  // outgoing: NT on planes
        k_plane_gemm<false><<<dim3(64, 4, 4), blk, 0, stream>>>(b1, b2, b3);
      else         // incoming: TN on planes
        k_plane_gemm<true><<<dim3(64, 4, 4), blk, 0, stream>>>(b2, b1, b3);
      k_gate<<<1024, blk, 0, stream>>>(
          b3, xln, tm_cln_s + bi*64, tm_cln_b + bi*64,
          tm_ow + bi*4096, tm_ob + bi*64, tm_gw + bi*4096, tm_gb + bi*64, act);
    }
    // ---- transition ----
    k_ln<<<2048, blk, 0, stream>>>(act, xln, tr_ln_s + B*64, tr_ln_b + B*64, 0);
    k_gemm<2,false,false><<<dim3(1024, 2), blk, 0, stream>>>(
        xln, 64, 128, tr_w1 + B*8192, tr_b1 + B*128, b1);
    k_gemm<0,true,false><<<dim3(1024, 1), blk, 0, stream>>>(
        b1, 128, 64, tr_w2 + B*8192, tr_b2 + B*64, act);
  }

  k_ln<<<2048, blk, 0, stream>>>(act, (float*)d_out, out_ln_s, out_ln_b, 0);
}

// Round 9
// 2402.414 us; speedup vs baseline: 3.2268x; 3.2268x over previous
//
#include <hip/hip_runtime.h>

#define NRES 256
#define P_TOT (NRES*NRES)
#define P64   (P_TOT*64)

#define FMA16(A4, B4, ACC) do { \
  ACC[0][0] += A4.x*B4.x; ACC[0][1] += A4.x*B4.y; ACC[0][2] += A4.x*B4.z; ACC[0][3] += A4.x*B4.w; \
  ACC[1][0] += A4.y*B4.x; ACC[1][1] += A4.y*B4.y; ACC[1][2] += A4.y*B4.z; ACC[1][3] += A4.y*B4.w; \
  ACC[2][0] += A4.z*B4.x; ACC[2][1] += A4.z*B4.y; ACC[2][2] += A4.z*B4.z; ACC[2][3] += A4.z*B4.w; \
  ACC[3][0] += A4.w*B4.x; ACC[3][1] += A4.w*B4.y; ACC[3][2] += A4.w*B4.z; ACC[3][3] += A4.w*B4.w; \
} while (0)

__device__ __forceinline__ float sgm(float x) { return 1.0f / (1.0f + __expf(-x)); }

// ---------------------------------------------------------------------------
// Backbone frames: rot (pre-swapaxes) + trans, 12 floats per residue.
// ---------------------------------------------------------------------------
__global__ void k_transform(const float* __restrict__ pos, float* __restrict__ rt) {
  int i = threadIdx.x;
  if (i >= NRES) return;
  const float* p = pos + i*37*3;
  float nx = p[0], ny = p[1], nz = p[2];
  float cax = p[3], cay = p[4], caz = p[5];
  float ccx = p[6], ccy = p[7], ccz = p[8];
  float c0x = ccx - cax, c0y = ccy - cay, c0z = ccz - caz;
  float n0x = nx - cax, n0y = ny - cay, n0z = nz - caz;
  float norm1 = sqrtf(1e-20f + c0x*c0x + c0y*c0y);
  float s1 = -c0y / norm1, c1 = c0x / norm1;
  float norm2 = sqrtf(1e-20f + c0x*c0x + c0y*c0y + c0z*c0z);
  float s2 = c0z / norm2, c2 = sqrtf(c0x*c0x + c0y*c0y) / norm2;
  float r00 = c2*c1,   r01 = -c2*s1,  r02 = s2;
  float r10 = s1,      r11 = c1,      r12 = 0.f;
  float r20 = -s2*c1,  r21 = s2*s1,   r22 = c2;
  float py = r10*n0x + r11*n0y + r12*n0z;
  float pz = r20*n0x + r21*n0y + r22*n0z;
  float norm3 = sqrtf(1e-20f + py*py + pz*pz);
  float sn = -pz / norm3, cn = py / norm3;
  float* o = rt + i*12;
  o[0] = r00; o[1] = r01; o[2] = r02;
  o[3] = cn*r10 - sn*r20; o[4] = cn*r11 - sn*r21; o[5] = cn*r12 - sn*r22;
  o[6] = sn*r10 + cn*r20; o[7] = sn*r11 + cn*r21; o[8] = sn*r12 + cn*r22;
  o[9] = cax; o[10] = cay; o[11] = caz;
}

// ---------------------------------------------------------------------------
// Features -> embedding. feat = 8 nonzero rows of emb_w (one-hots collapse).
// Phase 1: thread j computes coefficients -> LDS. Phase 2: lane = channel,
// wave = j-subgroup -> coalesced 256B stores.
// ---------------------------------------------------------------------------
__global__ __launch_bounds__(256) void k_feat_embed(
    const int* __restrict__ aatype, const float* __restrict__ bmask,
    const float* __restrict__ beta, const float* __restrict__ amask,
    const float* __restrict__ rt, const float* __restrict__ emb_w,
    const float* __restrict__ emb_b, float* __restrict__ act) {
  __shared__ float ew[88][68];
  __shared__ float eb[64];
  __shared__ float cf[5][256];   // bm2, ux, uy, uz, bb2 per j
  __shared__ int   ci[2][256];   // bin, rj per j
  int t = threadIdx.x;
  for (int idx = t; idx < 88*64; idx += 256) ew[idx >> 6][idx & 63] = emb_w[idx];
  if (t < 64) eb[t] = emb_b[t];
  int i = blockIdx.x;
  {
    int j = t;
    float bm2 = bmask[i] * bmask[j];
    float dx = beta[i*3+0] - beta[j*3+0];
    float dy = beta[i*3+1] - beta[j*3+1];
    float dz = beta[i*3+2] - beta[j*3+2];
    float d2 = dx*dx + dy*dy + dz*dz;
    int bin = -1;
    for (int k = 0; k < 39; k++) {
      float lk = 3.25f + 1.25f * (float)k;
      float lo = lk * lk;
      float up = (k == 38) ? 1e8f : (lk + 1.25f) * (lk + 1.25f);
      if (d2 > lo && d2 < up) bin = k;
    }
    int aaj = aatype[j];
    float bbi = amask[i*37+0] * amask[i*37+1] * amask[i*37+2];
    float bbj = amask[j*37+0] * amask[j*37+1] * amask[j*37+2];
    float bb2 = bbi * bbj;
    const float* R = rt + i*12;
    float tx = rt[j*12+9]  - R[9];
    float ty = rt[j*12+10] - R[10];
    float tz = rt[j*12+11] - R[11];
    float ax = R[0]*tx + R[1]*ty + R[2]*tz;
    float ay = R[3]*tx + R[4]*ty + R[5]*tz;
    float az = R[6]*tx + R[7]*ty + R[8]*tz;
    float f = (1.0f / sqrtf(1e-6f + ax*ax + ay*ay + az*az)) * bb2;
    cf[0][j] = bm2;
    cf[1][j] = ax*f; cf[2][j] = ay*f; cf[3][j] = az*f;
    cf[4][j] = bb2;
    ci[0][j] = bin;
    ci[1][j] = 40 + aaj;
  }
  __syncthreads();
  int ri = 62 + aatype[i];
  int c = t & 63, js = t >> 6;
  for (int jj = 0; jj < 64; jj++) {
    int j = jj*4 + js;
    float bm2 = cf[0][j], ux = cf[1][j], uy = cf[2][j], uz = cf[3][j], bb2 = cf[4][j];
    int bin = ci[0][j], rj = ci[1][j];
    float a = (bin >= 0 ? ew[bin][c] : 0.f) + bm2*ew[39][c] + ew[rj][c] + ew[ri][c]
            + ux*ew[84][c] + uy*ew[85][c] + uz*ew[86][c] + bb2*ew[87][c];
    act[((size_t)i*NRES + j)*64 + c] = bb2*a + eb[c];
  }
}

// ---------------------------------------------------------------------------
// LayerNorm over last dim (64). One wave per row, lane = channel.
// ---------------------------------------------------------------------------
__global__ __launch_bounds__(256) void k_ln(const float* __restrict__ src, float* __restrict__ dst,
                                            const float* __restrict__ s, const float* __restrict__ b,
                                            int transpose) {
  int lane = threadIdx.x & 63;
  int wave = blockIdx.x * (blockDim.x >> 6) + (threadIdx.x >> 6);
  int nw = gridDim.x * (blockDim.x >> 6);
  float sc = s[lane], bc = b[lane];
  for (int p = wave; p < P_TOT; p += nw) {
    int sp = transpose ? ((p & 255)*NRES + (p >> 8)) : p;
    float x = src[sp*64 + lane];
    float mu = x;
    for (int o = 1; o < 64; o <<= 1) mu += __shfl_xor(mu, o);
    mu *= (1.0f/64.0f);
    float d = x - mu;
    float v = d*d;
    for (int o = 1; o < 64; o <<= 1) v += __shfl_xor(v, o);
    v *= (1.0f/64.0f);
    dst[p*64 + lane] = d * (1.0f / sqrtf(v + 1e-5f)) * sc + bc;
  }
}

// ---------------------------------------------------------------------------
// nbT[h][k][q] = sum_c xln[(q,k),c] * f2d[c,h]. Coalesced writes (lane=q).
// ---------------------------------------------------------------------------
__global__ __launch_bounds__(256) void k_nb(
    const float* __restrict__ xln, const float* __restrict__ f2d,
    float* __restrict__ nbT) {
  __shared__ float fs[64][4];
  int t = threadIdx.x;
  fs[t >> 2][t & 3] = f2d[t];
  __syncthreads();
  int k = blockIdx.x, q = t;
  const float4* xr = (const float4*)(xln + ((size_t)q*NRES + k)*64);
  float a0 = 0, a1 = 0, a2 = 0, a3 = 0;
  #pragma unroll
  for (int c4 = 0; c4 < 16; c4++) {
    float4 xv = xr[c4];
    int c = c4*4;
    a0 += xv.x*fs[c][0] + xv.y*fs[c+1][0] + xv.z*fs[c+2][0] + xv.w*fs[c+3][0];
    a1 += xv.x*fs[c][1] + xv.y*fs[c+1][1] + xv.z*fs[c+2][1] + xv.w*fs[c+3][1];
    a2 += xv.x*fs[c][2] + xv.y*fs[c+1][2] + xv.z*fs[c+2][2] + xv.w*fs[c+3][2];
    a3 += xv.x*fs[c][3] + xv.y*fs[c+1][3] + xv.z*fs[c+2][3] + xv.w*fs[c+3][3];
  }
  int base = k*NRES + q;
  nbT[base]          = a0;
  nbT[65536  + base] = a1;
  nbT[131072 + base] = a2;
  nbT[196608 + base] = a3;
}

// ---------------------------------------------------------------------------
// Fused q/k/v/gate projections: ONE pass over X (staged once), loop the 4
// weight sets in-block. ti=t>>4 rows / tj=t&15 cols -> coalesced stores.
// NOTE: no min-waves launch bound — (256,4) clamped VGPR to 64 and spilled
// 5.3 GB/dispatch to scratch (round-7 profile).
// ---------------------------------------------------------------------------
__global__ __launch_bounds__(256) void k_proj(
    const float* __restrict__ X,
    const float* __restrict__ QW, const float* __restrict__ KW,
    const float* __restrict__ VW, const float* __restrict__ GW,
    const float* __restrict__ GBb,
    float* __restrict__ Yq, float* __restrict__ Yk,
    float* __restrict__ Yv, float* __restrict__ Yg) {
  __shared__ float Xs[64][68];
  __shared__ float Ws[64][68];
  int t = threadIdx.x, ti = t >> 4, tj = t & 15;
  int p0 = blockIdx.x * 64;
  #pragma unroll
  for (int e = 0; e < 16; e++) {
    int idx = t + e*256;
    int r = idx >> 6, c = idx & 63;
    Xs[c][r] = X[(size_t)(p0 + r)*64 + c];
  }
  for (int sel = 0; sel < 4; sel++) {
    const float* W = sel == 0 ? QW : sel == 1 ? KW : sel == 2 ? VW : GW;
    float* Y = sel == 0 ? Yq : sel == 1 ? Yk : sel == 2 ? Yv : Yg;
    #pragma unroll
    for (int e = 0; e < 16; e++) {
      int idx = t + e*256;
      Ws[idx >> 6][idx & 63] = W[idx];
    }
    __syncthreads();
    float acc[4][4] = {{0}};
    #pragma unroll
    for (int kk = 0; kk < 64; kk++) {
      float4 a = *((const float4*)&Xs[kk][ti*4]);
      float4 b = *((const float4*)&Ws[kk][tj*4]);
      FMA16(a, b, acc);
    }
    __syncthreads();   // all waves done with Ws before next restage
    float gb4[4] = {0,0,0,0};
    if (sel == 3) {
      #pragma unroll
      for (int v = 0; v < 4; v++) gb4[v] = GBb[tj*4 + v];
    }
    float scale = (sel == 0) ? 0.25f : 1.0f;
    #pragma unroll
    for (int u = 0; u < 4; u++) {
      int p = p0 + ti*4 + u;
      float4 o;
      if (sel == 3) {
        o.x = sgm(acc[u][0] + gb4[0]); o.y = sgm(acc[u][1] + gb4[1]);
        o.z = sgm(acc[u][2] + gb4[2]); o.w = sgm(acc[u][3] + gb4[3]);
      } else {
        o.x = acc[u][0]*scale; o.y = acc[u][1]*scale;
        o.z = acc[u][2]*scale; o.w = acc[u][3]*scale;
      }
      *((float4*)&Y[(size_t)p*64 + tj*4]) = o;
    }
  }
}

// ---------------------------------------------------------------------------
// Flash attention per (b,h), no max-tracking (logits analytically bounded).
// 128 threads, 2 queries per thread. Writes (wa*gate) in-place into Q.
// ---------------------------------------------------------------------------
__global__ __launch_bounds__(128) void k_attn(
    float* __restrict__ Q, const float* __restrict__ Kb, const float* __restrict__ Vb,
    const float* __restrict__ G, const float* __restrict__ nbT,
    const float* __restrict__ mask, int ending) {
  __shared__ float ks[256][16];
  __shared__ float vs[256][16];
  __shared__ float bs[256];
  int b = blockIdx.x, h = blockIdx.y;
  int t = threadIdx.x;
  #pragma unroll
  for (int s = 0; s < 2; s++) {
    int k = t + s*128;
    const float4* kr = (const float4*)(Kb + ((size_t)b*NRES + k)*64 + h*16);
    const float4* vr = (const float4*)(Vb + ((size_t)b*NRES + k)*64 + h*16);
    float4* kd = (float4*)ks[k];
    float4* vd = (float4*)vs[k];
    #pragma unroll
    for (int d4 = 0; d4 < 4; d4++) { kd[d4] = kr[d4]; vd[d4] = vr[d4]; }
    float m = ending ? mask[k*NRES + b] : mask[b*NRES + k];
    bs[k] = 1e9f * (m - 1.0f);
  }
  __syncthreads();
  int q0 = t, q1 = t + 128;
  float* qr0 = Q + ((size_t)b*NRES + q0)*64 + h*16;
  float* qr1 = Q + ((size_t)b*NRES + q1)*64 + h*16;
  float4 qv0[4], qv1[4];
  #pragma unroll
  for (int d4 = 0; d4 < 4; d4++) { qv0[d4] = ((const float4*)qr0)[d4]; qv1[d4] = ((const float4*)qr1)[d4]; }
  const float* nbr = nbT + h*65536;
  float l0 = 0.0f, l1 = 0.0f;
  float acc0[16], acc1[16];
  #pragma unroll
  for (int d = 0; d < 16; d++) { acc0[d] = 0.0f; acc1[d] = 0.0f; }
  #pragma unroll 2
  for (int k = 0; k < 256; k++) {
    float dot0 = 0.0f, dot1 = 0.0f;
    #pragma unroll
    for (int d4 = 0; d4 < 4; d4++) {
      float4 kv = *((const float4*)&ks[k][d4*4]);
      dot0 += qv0[d4].x*kv.x + qv0[d4].y*kv.y + qv0[d4].z*kv.z + qv0[d4].w*kv.w;
      dot1 += qv1[d4].x*kv.x + qv1[d4].y*kv.y + qv1[d4].z*kv.z + qv1[d4].w*kv.w;
    }
    float bk = bs[k];
    float p0 = __expf(dot0 + bk + nbr[(k << 8) + q0]);
    float p1 = __expf(dot1 + bk + nbr[(k << 8) + q1]);
    l0 += p0; l1 += p1;
    #pragma unroll
    for (int d4 = 0; d4 < 4; d4++) {
      float4 vv = *((const float4*)&vs[k][d4*4]);
      acc0[d4*4+0] += p0*vv.x; acc0[d4*4+1] += p0*vv.y;
      acc0[d4*4+2] += p0*vv.z; acc0[d4*4+3] += p0*vv.w;
      acc1[d4*4+0] += p1*vv.x; acc1[d4*4+1] += p1*vv.y;
      acc1[d4*4+2] += p1*vv.z; acc1[d4*4+3] += p1*vv.w;
    }
  }
  float inv0 = 1.0f / l0, inv1 = 1.0f / l1;
  const float4* gr0 = (const float4*)(G + ((size_t)b*NRES + q0)*64 + h*16);
  const float4* gr1 = (const float4*)(G + ((size_t)b*NRES + q1)*64 + h*16);
  #pragma unroll
  for (int d4 = 0; d4 < 4; d4++) {
    float4 gv0 = gr0[d4], gv1 = gr1[d4];
    float4 o0, o1;
    o0.x = acc0[d4*4+0]*inv0*gv0.x; o0.y = acc0[d4*4+1]*inv0*gv0.y;
    o0.z = acc0[d4*4+2]*inv0*gv0.z; o0.w = acc0[d4*4+3]*inv0*gv0.w;
    o1.x = acc1[d4*4+0]*inv1*gv1.x; o1.y = acc1[d4*4+1]*inv1*gv1.y;
    o1.z = acc1[d4*4+2]*inv1*gv1.z; o1.w = acc1[d4*4+3]*inv1*gv1.w;
    ((float4*)qr0)[d4] = o0;
    ((float4*)qr1)[d4] = o1;
  }
}

// ---------------------------------------------------------------------------
// Generic tiled GEMM, coalesced-store microtile (ti=t>>4 rows, tj=t&15 cols).
// ---------------------------------------------------------------------------
template<int ACT, bool RESID, bool TRANSRES>
__global__ __launch_bounds__(256) void k_gemm(
    const float* __restrict__ X, int K, int N,
    const float* __restrict__ W, const float* __restrict__ B,
    float* __restrict__ Y) {
  __shared__ float Xs[64][68];
  __shared__ float Ws[64][68];
  int t = threadIdx.x, ti = t >> 4, tj = t & 15;
  int p0 = blockIdx.x * 64, n0 = blockIdx.y * 64;
  float acc[4][4] = {{0}};
  for (int kc = 0; kc < K; kc += 64) {
    #pragma unroll
    for (int e = 0; e < 16; e++) {
      int idx = t + e*256;
      int r = idx >> 6, c = idx & 63;
      Xs[c][r] = X[(size_t)(p0 + r)*K + kc + c];
      Ws[r][c] = W[(size_t)(kc + r)*N + n0 + c];
    }
    __syncthreads();
    #pragma unroll
    for (int kk = 0; kk < 64; kk++) {
      float4 a = *((const float4*)&Xs[kk][ti*4]);
      float4 b = *((const float4*)&Ws[kk][tj*4]);
      FMA16(a, b, acc);
    }
    __syncthreads();
  }
  float bv[4] = {0,0,0,0};
  if (B) {
    #pragma unroll
    for (int v = 0; v < 4; v++) bv[v] = B[n0 + tj*4 + v];
  }
  #pragma unroll
  for (int u = 0; u < 4; u++) {
    int p = p0 + ti*4 + u;
    float res[4];
    #pragma unroll
    for (int v = 0; v < 4; v++) {
      float val = acc[u][v] + bv[v];
      if (ACT == 1) val = sgm(val);
      if (ACT == 2) val = fmaxf(val, 0.0f);
      res[v] = val;
    }
    if (RESID) {
      int row = TRANSRES ? ((p & 255)*NRES + (p >> 8)) : p;
      float4* yp = (float4*)&Y[(size_t)row*64 + n0 + tj*4];
      float4 old = *yp;
      old.x += res[0]; old.y += res[1]; old.z += res[2]; old.w += res[3];
      *yp = old;
    } else {
      *((float4*)&Y[(size_t)p*N + n0 + tj*4]) = make_float4(res[0], res[1], res[2], res[3]);
    }
  }
}

// ---------------------------------------------------------------------------
// Dual gated projection for triangle-mult, writing in plane layout Y[c][p]
// via LDS retranspose.
// ---------------------------------------------------------------------------
__global__ __launch_bounds__(256) void k_dual2(
    const float* __restrict__ X,
    const float* __restrict__ PW0, const float* __restrict__ PB0,
    const float* __restrict__ GW0, const float* __restrict__ GB0,
    const float* __restrict__ PW1, const float* __restrict__ PB1,
    const float* __restrict__ GW1, const float* __restrict__ GB1,
    const float* __restrict__ mask,
    float* __restrict__ Y0, float* __restrict__ Y1) {
  __shared__ float Xs[64][68];
  __shared__ float Wp[64][68];
  __shared__ float Wg[64][68];
  int t = threadIdx.x, ti = t & 15, tj = t >> 4;
  int p0 = blockIdx.x * 64, sel = blockIdx.y;
  const float* PW = sel ? PW1 : PW0;
  const float* PB = sel ? PB1 : PB0;
  const float* GW = sel ? GW1 : GW0;
  const float* GB = sel ? GB1 : GB0;
  float* Y = sel ? Y1 : Y0;
  #pragma unroll
  for (int e = 0; e < 16; e++) {
    int idx = t + e*256;
    int r = idx >> 6, c = idx & 63;
    Xs[c][r] = X[(size_t)(p0 + r)*64 + c];
    Wp[r][c] = PW[idx];
    Wg[r][c] = GW[idx];
  }
  __syncthreads();
  float acc1[4][4] = {{0}};
  float acc2[4][4] = {{0}};
  #pragma unroll
  for (int kk = 0; kk < 64; kk++) {
    float4 a  = *((const float4*)&Xs[kk][ti*4]);
    float4 b1 = *((const float4*)&Wp[kk][tj*4]);
    FMA16(a, b1, acc1);
    float4 b2 = *((const float4*)&Wg[kk][tj*4]);
    FMA16(a, b2, acc2);
  }
  __syncthreads();   // done reading Wp; reuse it as retranspose tile [n][r]
  float pb4[4], gb4[4];
  #pragma unroll
  for (int v = 0; v < 4; v++) { pb4[v] = PB[tj*4 + v]; gb4[v] = GB[tj*4 + v]; }
  #pragma unroll
  for (int u = 0; u < 4; u++) {
    int p = p0 + ti*4 + u;
    float mp = mask[p];
    #pragma unroll
    for (int v = 0; v < 4; v++) {
      Wp[tj*4 + v][ti*4 + u] = mp * (acc1[u][v] + pb4[v]) * sgm(acc2[u][v] + gb4[v]);
    }
  }
  __syncthreads();
  #pragma unroll
  for (int e = 0; e < 16; e++) {
    int idx = t + e*256;
    int n = idx >> 6, r = idx & 63;
    Y[(size_t)n*65536 + p0 + r] = Wp[n][r];
  }
}

// ---------------------------------------------------------------------------
// 64 per-channel 256^3 GEMMs. NT: O=A·Bᵀ rows; TN: O=Aᵀ·B (planes [c][p]).
// ---------------------------------------------------------------------------
template<bool TN>
__global__ __launch_bounds__(256) void k_plane_gemm(const float* __restrict__ A,
                                                    const float* __restrict__ B,
                                                    float* __restrict__ O) {
  __shared__ float As[32][68];
  __shared__ float Bs[32][68];
  int c = blockIdx.x, it = blockIdx.y, jt = blockIdx.z;
  const float* Ac = A + (size_t)c*65536;
  const float* Bc = B + (size_t)c*65536;
  int t = threadIdx.x, ti = t >> 4, tj = t & 15;
  float acc[4][4] = {{0}};
  for (int k0 = 0; k0 < 256; k0 += 32) {
    if (TN) {
      #pragma unroll
      for (int e = 0; e < 8; e++) {
        int idx = t + e*256;
        int kk = idx >> 6, r = idx & 63;
        As[kk][r] = Ac[(k0 + kk)*NRES + it*64 + r];
        Bs[kk][r] = Bc[(k0 + kk)*NRES + jt*64 + r];
      }
    } else {
      #pragma unroll
      for (int e = 0; e < 8; e++) {
        int idx = t + e*256;
        int r = idx >> 5, kk = idx & 31;
        As[kk][r] = Ac[(it*64 + r)*NRES + k0 + kk];
        Bs[kk][r] = Bc[(jt*64 + r)*NRES + k0 + kk];
      }
    }
    __syncthreads();
    #pragma unroll
    for (int kk = 0; kk < 32; kk++) {
      float4 a = *((const float4*)&As[kk][ti*4]);
      float4 b = *((const float4*)&Bs[kk][tj*4]);
      FMA16(a, b, acc);
    }
    __syncthreads();
  }
  int ib = it*64 + ti*4, jb = jt*64 + tj*4;
  #pragma unroll
  for (int u = 0; u < 4; u++) {
    *((float4*)&O[(size_t)c*65536 + (ib + u)*NRES + jb]) =
        make_float4(acc[u][0], acc[u][1], acc[u][2], acc[u][3]);
  }
}

// ---------------------------------------------------------------------------
// Tri-mult epilogue as dual GEMM with LN fused into the A-tile load.
// ---------------------------------------------------------------------------
__global__ __launch_bounds__(256) void k_gate(
    const float* __restrict__ OT, const float* __restrict__ X2,
    const float* __restrict__ cs, const float* __restrict__ cb,
    const float* __restrict__ OW, const float* __restrict__ OB,
    const float* __restrict__ GW, const float* __restrict__ GB,
    float* __restrict__ act) {
  __shared__ float Xs[64][68];
  __shared__ float X2s[64][68];
  __shared__ float Wo[64][68];
  __shared__ float Wg[64][68];
  __shared__ float red[4][64];
  __shared__ float mrs[2][64];
  __shared__ float cln[2][64];
  int t = threadIdx.x, ti = t >> 4, tj = t & 15;
  int p0 = blockIdx.x * 64;
  if (t < 64) { cln[0][t] = cs[t]; cln[1][t] = cb[t]; }
  #pragma unroll
  for (int e = 0; e < 16; e++) {
    int idx = t + e*256;
    int rA = idx & 63, cA = idx >> 6;
    Xs[cA][rA]  = OT[(size_t)cA*65536 + p0 + rA];   // lanes walk rA: coalesced
    X2s[rA][cA] = X2[(size_t)(p0 + cA)*64 + rA];    // lanes walk rA (=channel)
    Wo[cA][rA]  = OW[idx];
    Wg[cA][rA]  = GW[idx];
  }
  __syncthreads();
  // LN over channel (first index of Xs) per column r
  int s4 = t >> 6, r = t & 63;
  float p1 = 0.f;
  #pragma unroll
  for (int cc = 0; cc < 16; cc++) p1 += Xs[s4*16 + cc][r];
  red[s4][r] = p1;
  __syncthreads();
  if (t < 64) mrs[0][t] = (red[0][t] + red[1][t] + red[2][t] + red[3][t]) * 0.015625f;
  __syncthreads();
  float mu_ = mrs[0][r];
  float v1 = 0.f;
  #pragma unroll
  for (int cc = 0; cc < 16; cc++) { float d = Xs[s4*16 + cc][r] - mu_; v1 += d*d; }
  red[s4][r] = v1;
  __syncthreads();
  if (t < 64) {
    float v = (red[0][t] + red[1][t] + red[2][t] + red[3][t]) * 0.015625f;
    mrs[1][t] = 1.0f / sqrtf(v + 1e-5f);
  }
  __syncthreads();
  float rs_ = mrs[1][r];
  #pragma unroll
  for (int cc = 0; cc < 16; cc++) {
    int c = s4*16 + cc;
    Xs[c][r] = (Xs[c][r] - mu_) * rs_ * cln[0][c] + cln[1][c];
  }
  __syncthreads();
  float acc1[4][4] = {{0}};
  float acc2[4][4] = {{0}};
  #pragma unroll
  for (int kk = 0; kk < 64; kk++) {
    float4 a  = *((const float4*)&Xs[kk][ti*4]);
    float4 b1 = *((const float4*)&Wo[kk][tj*4]);
    FMA16(a, b1, acc1);
    float4 a2 = *((const float4*)&X2s[kk][ti*4]);
    float4 b2 = *((const float4*)&Wg[kk][tj*4]);
    FMA16(a2, b2, acc2);
  }
  float obv[4], gbv[4];
  #pragma unroll
  for (int v = 0; v < 4; v++) { obv[v] = OB[tj*4 + v]; gbv[v] = GB[tj*4 + v]; }
  #pragma unroll
  for (int u = 0; u < 4; u++) {
    int p = p0 + ti*4 + u;
    float4* yp = (float4*)&act[(size_t)p*64 + tj*4];
    float4 old = *yp;
    old.x += (acc1[u][0] + obv[0]) * sgm(acc2[u][0] + gbv[0]);
    old.y += (acc1[u][1] + obv[1]) * sgm(acc2[u][1] + gbv[1]);
    old.z += (acc1[u][2] + obv[2]) * sgm(acc2[u][2] + gbv[2]);
    old.w += (acc1[u][3] + obv[3]) * sgm(acc2[u][3] + gbv[3]);
    *yp = old;
  }
}

// ---------------------------------------------------------------------------
extern "C" void kernel_launch(void* const* d_in, const int* in_sizes, int n_in,
                              void* d_out, int out_size, void* d_ws, size_t ws_size,
                              hipStream_t stream) {
  const int*   aatype  = (const int*)d_in[1];
  const float* bmask   = (const float*)d_in[2];
  const float* beta    = (const float*)d_in[3];
  const float* apos    = (const float*)d_in[4];
  const float* amask   = (const float*)d_in[5];
  const float* mask2d  = (const float*)d_in[6];
  const float* emb_w   = (const float*)d_in[7];
  const float* emb_b   = (const float*)d_in[8];
  const float* out_ln_s = (const float*)d_in[9];
  const float* out_ln_b = (const float*)d_in[10];
  const float* ta_ln_s = (const float*)d_in[11];
  const float* ta_ln_b = (const float*)d_in[12];
  const float* ta_f2d  = (const float*)d_in[13];
  const float* ta_qw   = (const float*)d_in[14];
  const float* ta_kw   = (const float*)d_in[15];
  const float* ta_vw   = (const float*)d_in[16];
  const float* ta_gw   = (const float*)d_in[17];
  const float* ta_gb   = (const float*)d_in[18];
  const float* ta_ow   = (const float*)d_in[19];
  const float* ta_ob   = (const float*)d_in[20];
  const float* tm_ln_s = (const float*)d_in[21];
  const float* tm_ln_b = (const float*)d_in[22];
  const float* tm_lpw  = (const float*)d_in[23];
  const float* tm_lpb  = (const float*)d_in[24];
  const float* tm_lgw  = (const float*)d_in[25];
  const float* tm_lgb  = (const float*)d_in[26];
  const float* tm_rpw  = (const float*)d_in[27];
  const float* tm_rpb  = (const float*)d_in[28];
  const float* tm_rgw  = (const float*)d_in[29];
  const float* tm_rgb  = (const float*)d_in[30];
  const float* tm_cln_s = (const float*)d_in[31];
  const float* tm_cln_b = (const float*)d_in[32];
  const float* tm_ow   = (const float*)d_in[33];
  const float* tm_ob   = (const float*)d_in[34];
  const float* tm_gw   = (const float*)d_in[35];
  const float* tm_gb   = (const float*)d_in[36];
  const float* tr_ln_s = (const float*)d_in[37];
  const float* tr_ln_b = (const float*)d_in[38];
  const float* tr_w1   = (const float*)d_in[39];
  const float* tr_b1   = (const float*)d_in[40];
  const float* tr_w2   = (const float*)d_in[41];
  const float* tr_b2   = (const float*)d_in[42];

  float* ws  = (float*)d_ws;
  float* rt  = ws;                    // 4096
  float* act = ws + 4096;             // 4 M floats
  float* xln = act + P64;             // 4 M
  float* nbT = xln + P64;             // 256 K
  float* b0  = nbT + 262144;          // 4 M
  float* b1  = b0 + P64;              // 4 M
  float* b2  = b1 + P64;              // 4 M
  float* b3  = (float*)d_out;         // gate / plane scratch; final output

  dim3 blk(256);

  k_transform<<<1, blk, 0, stream>>>(apos, rt);
  k_feat_embed<<<256, blk, 0, stream>>>(aatype, bmask, beta, amask, rt, emb_w, emb_b, act);

  for (int B = 0; B < 2; B++) {
    // ---- triangle attention (starting e=0, ending e=1) ----
    for (int e = 0; e < 2; e++) {
      int bi = B*2 + e;
      k_ln<<<2048, blk, 0, stream>>>(act, xln, ta_ln_s + bi*64, ta_ln_b + bi*64, e);
      k_nb<<<256, blk, 0, stream>>>(xln, ta_f2d + bi*256, nbT);
      k_proj<<<dim3(1024), blk, 0, stream>>>(
          xln, ta_qw + bi*4096, ta_kw + bi*4096, ta_vw + bi*4096, ta_gw + bi*4096,
          ta_gb + bi*64, b0, b1, b2, b3);
      k_attn<<<dim3(256, 4), dim3(128), 0, stream>>>(b0, b1, b2, b3, nbT, mask2d, e);
      if (e == 0)
        k_gemm<0,true,false><<<dim3(1024, 1), blk, 0, stream>>>(
            b0, 64, 64, ta_ow + bi*4096, ta_ob + bi*64, act);
      else
        k_gemm<0,true,true><<<dim3(1024, 1), blk, 0, stream>>>(
            b0, 64, 64, ta_ow + bi*4096, ta_ob + bi*64, act);
    }
    // ---- triangle multiplication (outgoing e=0, incoming e=1) ----
    for (int e = 0; e < 2; e++) {
      int bi = B*2 + e;
      k_ln<<<2048, blk, 0, stream>>>(act, xln, tm_ln_s + bi*64, tm_ln_b + bi*64, 0);
      k_dual2<<<dim3(1024, 2), blk, 0, stream>>>(
          xln, tm_lpw + bi*4096, tm_lpb + bi*64, tm_lgw + bi*4096, tm_lgb + bi*64,
          tm_rpw + bi*4096, tm_rpb + bi*64, tm_rgw + bi*4096, tm_rgb + bi*64,
          mask2d, b1, b2);
      if (e == 0)  // outgoing: NT on planes
        k_plane_gemm<false><<<dim3(64, 4, 4), blk, 0, stream>>>(b1, b2, b3);
      else         // incoming: TN on planes
        k_plane_gemm<true><<<dim3(64, 4, 4), blk, 0, stream>>>(b2, b1, b3);
      k_gate<<<1024, blk, 0, stream>>>(
          b3, xln, tm_cln_s + bi*64, tm_cln_b + bi*64,
          tm_ow + bi*4096, tm_ob + bi*64, tm_gw + bi*4096, tm_gb + bi*64, act);
    }
    // ---- transition ----
    k_ln<<<2048, blk, 0, stream>>>(act, xln, tr_ln_s + B*64, tr_ln_b + B*64, 0);
    k_gemm<2,false,false><<<dim3(1024, 2), blk, 0, stream>>>(
        xln, 64, 128, tr_w1 + B*8192, tr_b1 + B*128, b1);
    k_gemm<0,true,false><<<dim3(1024, 1), blk, 0, stream>>>(
        b1, 128, 64, tr_w2 + B*8192, tr_b2 + B*64, act);
  }

  k_ln<<<2048, blk, 0, stream>>>(act, (float*)d_out, out_ln_s, out_ln_b, 0);
}

// Round 13
// 1466.554 us; speedup vs baseline: 5.2859x; 1.6381x over previous
//
#include <hip/hip_runtime.h>

#define NRES 256
#define P_TOT (NRES*NRES)
#define P64   (P_TOT*64)

#define FMA16(A4, B4, ACC) do { \
  ACC[0][0] += A4.x*B4.x; ACC[0][1] += A4.x*B4.y; ACC[0][2] += A4.x*B4.z; ACC[0][3] += A4.x*B4.w; \
  ACC[1][0] += A4.y*B4.x; ACC[1][1] += A4.y*B4.y; ACC[1][2] += A4.y*B4.z; ACC[1][3] += A4.y*B4.w; \
  ACC[2][0] += A4.z*B4.x; ACC[2][1] += A4.z*B4.y; ACC[2][2] += A4.z*B4.z; ACC[2][3] += A4.z*B4.w; \
  ACC[3][0] += A4.w*B4.x; ACC[3][1] += A4.w*B4.y; ACC[3][2] += A4.w*B4.z; ACC[3][3] += A4.w*B4.w; \
} while (0)

__device__ __forceinline__ float sgm(float x) { return 1.0f / (1.0f + __expf(-x)); }

// ---------------------------------------------------------------------------
// Backbone frames: rot (pre-swapaxes) + trans, 12 floats per residue.
// ---------------------------------------------------------------------------
__global__ void k_transform(const float* __restrict__ pos, float* __restrict__ rt) {
  int i = threadIdx.x;
  if (i >= NRES) return;
  const float* p = pos + i*37*3;
  float nx = p[0], ny = p[1], nz = p[2];
  float cax = p[3], cay = p[4], caz = p[5];
  float ccx = p[6], ccy = p[7], ccz = p[8];
  float c0x = ccx - cax, c0y = ccy - cay, c0z = ccz - caz;
  float n0x = nx - cax, n0y = ny - cay, n0z = nz - caz;
  float norm1 = sqrtf(1e-20f + c0x*c0x + c0y*c0y);
  float s1 = -c0y / norm1, c1 = c0x / norm1;
  float norm2 = sqrtf(1e-20f + c0x*c0x + c0y*c0y + c0z*c0z);
  float s2 = c0z / norm2, c2 = sqrtf(c0x*c0x + c0y*c0y) / norm2;
  float r00 = c2*c1,   r01 = -c2*s1,  r02 = s2;
  float r10 = s1,      r11 = c1,      r12 = 0.f;
  float r20 = -s2*c1,  r21 = s2*s1,   r22 = c2;
  float py = r10*n0x + r11*n0y + r12*n0z;
  float pz = r20*n0x + r21*n0y + r22*n0z;
  float norm3 = sqrtf(1e-20f + py*py + pz*pz);
  float sn = -pz / norm3, cn = py / norm3;
  float* o = rt + i*12;
  o[0] = r00; o[1] = r01; o[2] = r02;
  o[3] = cn*r10 - sn*r20; o[4] = cn*r11 - sn*r21; o[5] = cn*r12 - sn*r22;
  o[6] = sn*r10 + cn*r20; o[7] = sn*r11 + cn*r21; o[8] = sn*r12 + cn*r22;
  o[9] = cax; o[10] = cay; o[11] = caz;
}

// ---------------------------------------------------------------------------
// Features -> embedding. feat = 8 nonzero rows of emb_w (one-hots collapse).
// Phase 1: thread j computes coefficients -> LDS. Phase 2: lane = channel,
// wave = j-subgroup -> coalesced 256B stores.
// ---------------------------------------------------------------------------
__global__ __launch_bounds__(256) void k_feat_embed(
    const int* __restrict__ aatype, const float* __restrict__ bmask,
    const float* __restrict__ beta, const float* __restrict__ amask,
    const float* __restrict__ rt, const float* __restrict__ emb_w,
    const float* __restrict__ emb_b, float* __restrict__ act) {
  __shared__ float ew[88][68];
  __shared__ float eb[64];
  __shared__ float cf[5][256];   // bm2, ux, uy, uz, bb2 per j
  __shared__ int   ci[2][256];   // bin, rj per j
  int t = threadIdx.x;
  for (int idx = t; idx < 88*64; idx += 256) ew[idx >> 6][idx & 63] = emb_w[idx];
  if (t < 64) eb[t] = emb_b[t];
  int i = blockIdx.x;
  {
    int j = t;
    float bm2 = bmask[i] * bmask[j];
    float dx = beta[i*3+0] - beta[j*3+0];
    float dy = beta[i*3+1] - beta[j*3+1];
    float dz = beta[i*3+2] - beta[j*3+2];
    float d2 = dx*dx + dy*dy + dz*dz;
    int bin = -1;
    for (int k = 0; k < 39; k++) {
      float lk = 3.25f + 1.25f * (float)k;
      float lo = lk * lk;
      float up = (k == 38) ? 1e8f : (lk + 1.25f) * (lk + 1.25f);
      if (d2 > lo && d2 < up) bin = k;
    }
    int aaj = aatype[j];
    float bbi = amask[i*37+0] * amask[i*37+1] * amask[i*37+2];
    float bbj = amask[j*37+0] * amask[j*37+1] * amask[j*37+2];
    float bb2 = bbi * bbj;
    const float* R = rt + i*12;
    float tx = rt[j*12+9]  - R[9];
    float ty = rt[j*12+10] - R[10];
    float tz = rt[j*12+11] - R[11];
    float ax = R[0]*tx + R[1]*ty + R[2]*tz;
    float ay = R[3]*tx + R[4]*ty + R[5]*tz;
    float az = R[6]*tx + R[7]*ty + R[8]*tz;
    float f = (1.0f / sqrtf(1e-6f + ax*ax + ay*ay + az*az)) * bb2;
    cf[0][j] = bm2;
    cf[1][j] = ax*f; cf[2][j] = ay*f; cf[3][j] = az*f;
    cf[4][j] = bb2;
    ci[0][j] = bin;
    ci[1][j] = 40 + aaj;
  }
  __syncthreads();
  int ri = 62 + aatype[i];
  int c = t & 63, js = t >> 6;
  for (int jj = 0; jj < 64; jj++) {
    int j = jj*4 + js;
    float bm2 = cf[0][j], ux = cf[1][j], uy = cf[2][j], uz = cf[3][j], bb2 = cf[4][j];
    int bin = ci[0][j], rj = ci[1][j];
    float a = (bin >= 0 ? ew[bin][c] : 0.f) + bm2*ew[39][c] + ew[rj][c] + ew[ri][c]
            + ux*ew[84][c] + uy*ew[85][c] + uz*ew[86][c] + bb2*ew[87][c];
    act[((size_t)i*NRES + j)*64 + c] = bb2*a + eb[c];
  }
}

// ---------------------------------------------------------------------------
// LayerNorm over last dim (64). One wave per row, lane = channel.
// ---------------------------------------------------------------------------
__global__ __launch_bounds__(256) void k_ln(const float* __restrict__ src, float* __restrict__ dst,
                                            const float* __restrict__ s, const float* __restrict__ b,
                                            int transpose) {
  int lane = threadIdx.x & 63;
  int wave = blockIdx.x * (blockDim.x >> 6) + (threadIdx.x >> 6);
  int nw = gridDim.x * (blockDim.x >> 6);
  float sc = s[lane], bc = b[lane];
  for (int p = wave; p < P_TOT; p += nw) {
    int sp = transpose ? ((p & 255)*NRES + (p >> 8)) : p;
    float x = src[sp*64 + lane];
    float mu = x;
    for (int o = 1; o < 64; o <<= 1) mu += __shfl_xor(mu, o);
    mu *= (1.0f/64.0f);
    float d = x - mu;
    float v = d*d;
    for (int o = 1; o < 64; o <<= 1) v += __shfl_xor(v, o);
    v *= (1.0f/64.0f);
    dst[p*64 + lane] = d * (1.0f / sqrtf(v + 1e-5f)) * sc + bc;
  }
}

// ---------------------------------------------------------------------------
// nbT[h][k][q] = sum_c xln[(q,k),c] * f2d[c,h]. Coalesced writes (lane=q).
// ---------------------------------------------------------------------------
__global__ __launch_bounds__(256) void k_nb(
    const float* __restrict__ xln, const float* __restrict__ f2d,
    float* __restrict__ nbT) {
  __shared__ float fs[64][4];
  int t = threadIdx.x;
  fs[t >> 2][t & 3] = f2d[t];
  __syncthreads();
  int k = blockIdx.x, q = t;
  const float4* xr = (const float4*)(xln + ((size_t)q*NRES + k)*64);
  float a0 = 0, a1 = 0, a2 = 0, a3 = 0;
  #pragma unroll
  for (int c4 = 0; c4 < 16; c4++) {
    float4 xv = xr[c4];
    int c = c4*4;
    a0 += xv.x*fs[c][0] + xv.y*fs[c+1][0] + xv.z*fs[c+2][0] + xv.w*fs[c+3][0];
    a1 += xv.x*fs[c][1] + xv.y*fs[c+1][1] + xv.z*fs[c+2][1] + xv.w*fs[c+3][1];
    a2 += xv.x*fs[c][2] + xv.y*fs[c+1][2] + xv.z*fs[c+2][2] + xv.w*fs[c+3][2];
    a3 += xv.x*fs[c][3] + xv.y*fs[c+1][3] + xv.z*fs[c+2][3] + xv.w*fs[c+3][3];
  }
  int base = k*NRES + q;
  nbT[base]          = a0;
  nbT[65536  + base] = a1;
  nbT[131072 + base] = a2;
  nbT[196608 + base] = a3;
}

// ---------------------------------------------------------------------------
// Fused q/k/v/gate projections: ONE pass over X (staged once), loop the 4
// weight sets in-block. Coalesced stores (ti=t>>4 rows, tj=t&15 cols).
// #pragma unroll 8 bounds the scheduler's load-prefetch window: full unroll
// pushed VGPR demand past the 256 cap -> scratch spills (round-9: 437MB
// writes vs 64MB useful, occupancy 10.8%).
// ---------------------------------------------------------------------------
__global__ __launch_bounds__(256) void k_proj(
    const float* __restrict__ X,
    const float* __restrict__ QW, const float* __restrict__ KW,
    const float* __restrict__ VW, const float* __restrict__ GW,
    const float* __restrict__ GBb,
    float* __restrict__ Yq, float* __restrict__ Yk,
    float* __restrict__ Yv, float* __restrict__ Yg) {
  __shared__ float Xs[64][68];
  __shared__ float Ws[64][68];
  int t = threadIdx.x, ti = t >> 4, tj = t & 15;
  int p0 = blockIdx.x * 64;
  #pragma unroll
  for (int e = 0; e < 16; e++) {
    int idx = t + e*256;
    int r = idx >> 6, c = idx & 63;
    Xs[c][r] = X[(size_t)(p0 + r)*64 + c];
  }
  for (int sel = 0; sel < 4; sel++) {
    const float* W = sel == 0 ? QW : sel == 1 ? KW : sel == 2 ? VW : GW;
    float* Y = sel == 0 ? Yq : sel == 1 ? Yk : sel == 2 ? Yv : Yg;
    #pragma unroll
    for (int e = 0; e < 16; e++) {
      int idx = t + e*256;
      Ws[idx >> 6][idx & 63] = W[idx];
    }
    __syncthreads();
    float acc[4][4] = {{0}};
    #pragma unroll 8
    for (int kk = 0; kk < 64; kk++) {
      float4 a = *((const float4*)&Xs[kk][ti*4]);
      float4 b = *((const float4*)&Ws[kk][tj*4]);
      FMA16(a, b, acc);
    }
    __syncthreads();   // all waves done with Ws before next restage
    float gb4[4] = {0,0,0,0};
    if (sel == 3) {
      #pragma unroll
      for (int v = 0; v < 4; v++) gb4[v] = GBb[tj*4 + v];
    }
    float scale = (sel == 0) ? 0.25f : 1.0f;
    #pragma unroll
    for (int u = 0; u < 4; u++) {
      int p = p0 + ti*4 + u;
      float4 o;
      if (sel == 3) {
        o.x = sgm(acc[u][0] + gb4[0]); o.y = sgm(acc[u][1] + gb4[1]);
        o.z = sgm(acc[u][2] + gb4[2]); o.w = sgm(acc[u][3] + gb4[3]);
      } else {
        o.x = acc[u][0]*scale; o.y = acc[u][1]*scale;
        o.z = acc[u][2]*scale; o.w = acc[u][3]*scale;
      }
      *((float4*)&Y[(size_t)p*64 + tj*4]) = o;
    }
  }
}

// ---------------------------------------------------------------------------
// Flash attention per (b,h), no max-tracking (logits analytically bounded).
// 128 threads, 2 queries per thread. Writes (wa*gate) in-place into Q.
// ---------------------------------------------------------------------------
__global__ __launch_bounds__(128) void k_attn(
    float* __restrict__ Q, const float* __restrict__ Kb, const float* __restrict__ Vb,
    const float* __restrict__ G, const float* __restrict__ nbT,
    const float* __restrict__ mask, int ending) {
  __shared__ float ks[256][16];
  __shared__ float vs[256][16];
  __shared__ float bs[256];
  int b = blockIdx.x, h = blockIdx.y;
  int t = threadIdx.x;
  #pragma unroll
  for (int s = 0; s < 2; s++) {
    int k = t + s*128;
    const float4* kr = (const float4*)(Kb + ((size_t)b*NRES + k)*64 + h*16);
    const float4* vr = (const float4*)(Vb + ((size_t)b*NRES + k)*64 + h*16);
    float4* kd = (float4*)ks[k];
    float4* vd = (float4*)vs[k];
    #pragma unroll
    for (int d4 = 0; d4 < 4; d4++) { kd[d4] = kr[d4]; vd[d4] = vr[d4]; }
    float m = ending ? mask[k*NRES + b] : mask[b*NRES + k];
    bs[k] = 1e9f * (m - 1.0f);
  }
  __syncthreads();
  int q0 = t, q1 = t + 128;
  float* qr0 = Q + ((size_t)b*NRES + q0)*64 + h*16;
  float* qr1 = Q + ((size_t)b*NRES + q1)*64 + h*16;
  float4 qv0[4], qv1[4];
  #pragma unroll
  for (int d4 = 0; d4 < 4; d4++) { qv0[d4] = ((const float4*)qr0)[d4]; qv1[d4] = ((const float4*)qr1)[d4]; }
  const float* nbr = nbT + h*65536;
  float l0 = 0.0f, l1 = 0.0f;
  float acc0[16], acc1[16];
  #pragma unroll
  for (int d = 0; d < 16; d++) { acc0[d] = 0.0f; acc1[d] = 0.0f; }
  #pragma unroll 2
  for (int k = 0; k < 256; k++) {
    float dot0 = 0.0f, dot1 = 0.0f;
    #pragma unroll
    for (int d4 = 0; d4 < 4; d4++) {
      float4 kv = *((const float4*)&ks[k][d4*4]);
      dot0 += qv0[d4].x*kv.x + qv0[d4].y*kv.y + qv0[d4].z*kv.z + qv0[d4].w*kv.w;
      dot1 += qv1[d4].x*kv.x + qv1[d4].y*kv.y + qv1[d4].z*kv.z + qv1[d4].w*kv.w;
    }
    float bk = bs[k];
    float p0 = __expf(dot0 + bk + nbr[(k << 8) + q0]);
    float p1 = __expf(dot1 + bk + nbr[(k << 8) + q1]);
    l0 += p0; l1 += p1;
    #pragma unroll
    for (int d4 = 0; d4 < 4; d4++) {
      float4 vv = *((const float4*)&vs[k][d4*4]);
      acc0[d4*4+0] += p0*vv.x; acc0[d4*4+1] += p0*vv.y;
      acc0[d4*4+2] += p0*vv.z; acc0[d4*4+3] += p0*vv.w;
      acc1[d4*4+0] += p1*vv.x; acc1[d4*4+1] += p1*vv.y;
      acc1[d4*4+2] += p1*vv.z; acc1[d4*4+3] += p1*vv.w;
    }
  }
  float inv0 = 1.0f / l0, inv1 = 1.0f / l1;
  const float4* gr0 = (const float4*)(G + ((size_t)b*NRES + q0)*64 + h*16);
  const float4* gr1 = (const float4*)(G + ((size_t)b*NRES + q1)*64 + h*16);
  #pragma unroll
  for (int d4 = 0; d4 < 4; d4++) {
    float4 gv0 = gr0[d4], gv1 = gr1[d4];
    float4 o0, o1;
    o0.x = acc0[d4*4+0]*inv0*gv0.x; o0.y = acc0[d4*4+1]*inv0*gv0.y;
    o0.z = acc0[d4*4+2]*inv0*gv0.z; o0.w = acc0[d4*4+3]*inv0*gv0.w;
    o1.x = acc1[d4*4+0]*inv1*gv1.x; o1.y = acc1[d4*4+1]*inv1*gv1.y;
    o1.z = acc1[d4*4+2]*inv1*gv1.z; o1.w = acc1[d4*4+3]*inv1*gv1.w;
    ((float4*)qr0)[d4] = o0;
    ((float4*)qr1)[d4] = o1;
  }
}

// ---------------------------------------------------------------------------
// Generic tiled GEMM, coalesced-store microtile (ti=t>>4 rows, tj=t&15 cols).
// ---------------------------------------------------------------------------
template<int ACT, bool RESID, bool TRANSRES>
__global__ __launch_bounds__(256) void k_gemm(
    const float* __restrict__ X, int K, int N,
    const float* __restrict__ W, const float* __restrict__ B,
    float* __restrict__ Y) {
  __shared__ float Xs[64][68];
  __shared__ float Ws[64][68];
  int t = threadIdx.x, ti = t >> 4, tj = t & 15;
  int p0 = blockIdx.x * 64, n0 = blockIdx.y * 64;
  float acc[4][4] = {{0}};
  for (int kc = 0; kc < K; kc += 64) {
    #pragma unroll
    for (int e = 0; e < 16; e++) {
      int idx = t + e*256;
      int r = idx >> 6, c = idx & 63;
      Xs[c][r] = X[(size_t)(p0 + r)*K + kc + c];
      Ws[r][c] = W[(size_t)(kc + r)*N + n0 + c];
    }
    __syncthreads();
    #pragma unroll 8
    for (int kk = 0; kk < 64; kk++) {
      float4 a = *((const float4*)&Xs[kk][ti*4]);
      float4 b = *((const float4*)&Ws[kk][tj*4]);
      FMA16(a, b, acc);
    }
    __syncthreads();
  }
  float bv[4] = {0,0,0,0};
  if (B) {
    #pragma unroll
    for (int v = 0; v < 4; v++) bv[v] = B[n0 + tj*4 + v];
  }
  #pragma unroll
  for (int u = 0; u < 4; u++) {
    int p = p0 + ti*4 + u;
    float res[4];
    #pragma unroll
    for (int v = 0; v < 4; v++) {
      float val = acc[u][v] + bv[v];
      if (ACT == 1) val = sgm(val);
      if (ACT == 2) val = fmaxf(val, 0.0f);
      res[v] = val;
    }
    if (RESID) {
      int row = TRANSRES ? ((p & 255)*NRES + (p >> 8)) : p;
      float4* yp = (float4*)&Y[(size_t)row*64 + n0 + tj*4];
      float4 old = *yp;
      old.x += res[0]; old.y += res[1]; old.z += res[2]; old.w += res[3];
      *yp = old;
    } else {
      *((float4*)&Y[(size_t)p*N + n0 + tj*4]) = make_float4(res[0], res[1], res[2], res[3]);
    }
  }
}

// ---------------------------------------------------------------------------
// Dual gated projection for triangle-mult, writing in plane layout Y[c][p]
// via LDS retranspose.
// ---------------------------------------------------------------------------
__global__ __launch_bounds__(256) void k_dual2(
    const float* __restrict__ X,
    const float* __restrict__ PW0, const float* __restrict__ PB0,
    const float* __restrict__ GW0, const float* __restrict__ GB0,
    const float* __restrict__ PW1, const float* __restrict__ PB1,
    const float* __restrict__ GW1, const float* __restrict__ GB1,
    const float* __restrict__ mask,
    float* __restrict__ Y0, float* __restrict__ Y1) {
  __shared__ float Xs[64][68];
  __shared__ float Wp[64][68];
  __shared__ float Wg[64][68];
  int t = threadIdx.x, ti = t & 15, tj = t >> 4;
  int p0 = blockIdx.x * 64, sel = blockIdx.y;
  const float* PW = sel ? PW1 : PW0;
  const float* PB = sel ? PB1 : PB0;
  const float* GW = sel ? GW1 : GW0;
  const float* GB = sel ? GB1 : GB0;
  float* Y = sel ? Y1 : Y0;
  #pragma unroll
  for (int e = 0; e < 16; e++) {
    int idx = t + e*256;
    int r = idx >> 6, c = idx & 63;
    Xs[c][r] = X[(size_t)(p0 + r)*64 + c];
    Wp[r][c] = PW[idx];
    Wg[r][c] = GW[idx];
  }
  __syncthreads();
  float acc1[4][4] = {{0}};
  float acc2[4][4] = {{0}};
  #pragma unroll 8
  for (int kk = 0; kk < 64; kk++) {
    float4 a  = *((const float4*)&Xs[kk][ti*4]);
    float4 b1 = *((const float4*)&Wp[kk][tj*4]);
    FMA16(a, b1, acc1);
    float4 b2 = *((const float4*)&Wg[kk][tj*4]);
    FMA16(a, b2, acc2);
  }
  __syncthreads();   // done reading Wp; reuse it as retranspose tile [n][r]
  float pb4[4], gb4[4];
  #pragma unroll
  for (int v = 0; v < 4; v++) { pb4[v] = PB[tj*4 + v]; gb4[v] = GB[tj*4 + v]; }
  #pragma unroll
  for (int u = 0; u < 4; u++) {
    int p = p0 + ti*4 + u;
    float mp = mask[p];
    #pragma unroll
    for (int v = 0; v < 4; v++) {
      Wp[tj*4 + v][ti*4 + u] = mp * (acc1[u][v] + pb4[v]) * sgm(acc2[u][v] + gb4[v]);
    }
  }
  __syncthreads();
  #pragma unroll
  for (int e = 0; e < 16; e++) {
    int idx = t + e*256;
    int n = idx >> 6, r = idx & 63;
    Y[(size_t)n*65536 + p0 + r] = Wp[n][r];
  }
}

// ---------------------------------------------------------------------------
// 64 per-channel 256^3 GEMMs. NT: O=A·Bᵀ rows; TN: O=Aᵀ·B (planes [c][p]).
// ---------------------------------------------------------------------------
template<bool TN>
__global__ __launch_bounds__(256) void k_plane_gemm(const float* __restrict__ A,
                                                    const float* __restrict__ B,
                                                    float* __restrict__ O) {
  __shared__ float As[32][68];
  __shared__ float Bs[32][68];
  int c = blockIdx.x, it = blockIdx.y, jt = blockIdx.z;
  const float* Ac = A + (size_t)c*65536;
  const float* Bc = B + (size_t)c*65536;
  int t = threadIdx.x, ti = t >> 4, tj = t & 15;
  float acc[4][4] = {{0}};
  for (int k0 = 0; k0 < 256; k0 += 32) {
    if (TN) {
      #pragma unroll
      for (int e = 0; e < 8; e++) {
        int idx = t + e*256;
        int kk = idx >> 6, r = idx & 63;
        As[kk][r] = Ac[(k0 + kk)*NRES + it*64 + r];
        Bs[kk][r] = Bc[(k0 + kk)*NRES + jt*64 + r];
      }
    } else {
      #pragma unroll
      for (int e = 0; e < 8; e++) {
        int idx = t + e*256;
        int r = idx >> 5, kk = idx & 31;
        As[kk][r] = Ac[(it*64 + r)*NRES + k0 + kk];
        Bs[kk][r] = Bc[(jt*64 + r)*NRES + k0 + kk];
      }
    }
    __syncthreads();
    #pragma unroll 8
    for (int kk = 0; kk < 32; kk++) {
      float4 a = *((const float4*)&As[kk][ti*4]);
      float4 b = *((const float4*)&Bs[kk][tj*4]);
      FMA16(a, b, acc);
    }
    __syncthreads();
  }
  int ib = it*64 + ti*4, jb = jt*64 + tj*4;
  #pragma unroll
  for (int u = 0; u < 4; u++) {
    *((float4*)&O[(size_t)c*65536 + (ib + u)*NRES + jb]) =
        make_float4(acc[u][0], acc[u][1], acc[u][2], acc[u][3]);
  }
}

// ---------------------------------------------------------------------------
// Tri-mult epilogue as dual GEMM with LN fused into the A-tile load.
// ---------------------------------------------------------------------------
__global__ __launch_bounds__(256) void k_gate(
    const float* __restrict__ OT, const float* __restrict__ X2,
    const float* __restrict__ cs, const float* __restrict__ cb,
    const float* __restrict__ OW, const float* __restrict__ OB,
    const float* __restrict__ GW, const float* __restrict__ GB,
    float* __restrict__ act) {
  __shared__ float Xs[64][68];
  __shared__ float X2s[64][68];
  __shared__ float Wo[64][68];
  __shared__ float Wg[64][68];
  __shared__ float red[4][64];
  __shared__ float mrs[2][64];
  __shared__ float cln[2][64];
  int t = threadIdx.x, ti = t >> 4, tj = t & 15;
  int p0 = blockIdx.x * 64;
  if (t < 64) { cln[0][t] = cs[t]; cln[1][t] = cb[t]; }
  #pragma unroll
  for (int e = 0; e < 16; e++) {
    int idx = t + e*256;
    int rA = idx & 63, cA = idx >> 6;
    Xs[cA][rA]  = OT[(size_t)cA*65536 + p0 + rA];   // lanes walk rA: coalesced
    X2s[rA][cA] = X2[(size_t)(p0 + cA)*64 + rA];    // lanes walk rA (=channel)
    Wo[cA][rA]  = OW[idx];
    Wg[cA][rA]  = GW[idx];
  }
  __syncthreads();
  // LN over channel (first index of Xs) per column r
  int s4 = t >> 6, r = t & 63;
  float p1 = 0.f;
  #pragma unroll
  for (int cc = 0; cc < 16; cc++) p1 += Xs[s4*16 + cc][r];
  red[s4][r] = p1;
  __syncthreads();
  if (t < 64) mrs[0][t] = (red[0][t] + red[1][t] + red[2][t] + red[3][t]) * 0.015625f;
  __syncthreads();
  float mu_ = mrs[0][r];
  float v1 = 0.f;
  #pragma unroll
  for (int cc = 0; cc < 16; cc++) { float d = Xs[s4*16 + cc][r] - mu_; v1 += d*d; }
  red[s4][r] = v1;
  __syncthreads();
  if (t < 64) {
    float v = (red[0][t] + red[1][t] + red[2][t] + red[3][t]) * 0.015625f;
    mrs[1][t] = 1.0f / sqrtf(v + 1e-5f);
  }
  __syncthreads();
  float rs_ = mrs[1][r];
  #pragma unroll
  for (int cc = 0; cc < 16; cc++) {
    int c = s4*16 + cc;
    Xs[c][r] = (Xs[c][r] - mu_) * rs_ * cln[0][c] + cln[1][c];
  }
  __syncthreads();
  float acc1[4][4] = {{0}};
  float acc2[4][4] = {{0}};
  #pragma unroll 8
  for (int kk = 0; kk < 64; kk++) {
    float4 a  = *((const float4*)&Xs[kk][ti*4]);
    float4 b1 = *((const float4*)&Wo[kk][tj*4]);
    FMA16(a, b1, acc1);
    float4 a2 = *((const float4*)&X2s[kk][ti*4]);
    float4 b2 = *((const float4*)&Wg[kk][tj*4]);
    FMA16(a2, b2, acc2);
  }
  float obv[4], gbv[4];
  #pragma unroll
  for (int v = 0; v < 4; v++) { obv[v] = OB[tj*4 + v]; gbv[v] = GB[tj*4 + v]; }
  #pragma unroll
  for (int u = 0; u < 4; u++) {
    int p = p0 + ti*4 + u;
    float4* yp = (float4*)&act[(size_t)p*64 + tj*4];
    float4 old = *yp;
    old.x += (acc1[u][0] + obv[0]) * sgm(acc2[u][0] + gbv[0]);
    old.y += (acc1[u][1] + obv[1]) * sgm(acc2[u][1] + gbv[1]);
    old.z += (acc1[u][2] + obv[2]) * sgm(acc2[u][2] + gbv[2]);
    old.w += (acc1[u][3] + obv[3]) * sgm(acc2[u][3] + gbv[3]);
    *yp = old;
  }
}

// ---------------------------------------------------------------------------
extern "C" void kernel_launch(void* const* d_in, const int* in_sizes, int n_in,
                              void* d_out, int out_size, void* d_ws, size_t ws_size,
                              hipStream_t stream) {
  const int*   aatype  = (const int*)d_in[1];
  const float* bmask   = (const float*)d_in[2];
  const float* beta    = (const float*)d_in[3];
  const float* apos    = (const float*)d_in[4];
  const float* amask   = (const float*)d_in[5];
  const float* mask2d  = (const float*)d_in[6];
  const float* emb_w   = (const float*)d_in[7];
  const float* emb_b   = (const float*)d_in[8];
  const float* out_ln_s = (const float*)d_in[9];
  const float* out_ln_b = (const float*)d_in[10];
  const float* ta_ln_s = (const float*)d_in[11];
  const float* ta_ln_b = (const float*)d_in[12];
  const float* ta_f2d  = (const float*)d_in[13];
  const float* ta_qw   = (const float*)d_in[14];
  const float* ta_kw   = (const float*)d_in[15];
  const float* ta_vw   = (const float*)d_in[16];
  const float* ta_gw   = (const float*)d_in[17];
  const float* ta_gb   = (const float*)d_in[18];
  const float* ta_ow   = (const float*)d_in[19];
  const float* ta_ob   = (const float*)d_in[20];
  const float* tm_ln_s = (const float*)d_in[21];
  const float* tm_ln_b = (const float*)d_in[22];
  const float* tm_lpw  = (const float*)d_in[23];
  const float* tm_lpb  = (const float*)d_in[24];
  const float* tm_lgw  = (const float*)d_in[25];
  const float* tm_lgb  = (const float*)d_in[26];
  const float* tm_rpw  = (const float*)d_in[27];
  const float* tm_rpb  = (const float*)d_in[28];
  const float* tm_rgw  = (const float*)d_in[29];
  const float* tm_rgb  = (const float*)d_in[30];
  const float* tm_cln_s = (const float*)d_in[31];
  const float* tm_cln_b = (const float*)d_in[32];
  const float* tm_ow   = (const float*)d_in[33];
  const float* tm_ob   = (const float*)d_in[34];
  const float* tm_gw   = (const float*)d_in[35];
  const float* tm_gb   = (const float*)d_in[36];
  const float* tr_ln_s = (const float*)d_in[37];
  const float* tr_ln_b = (const float*)d_in[38];
  const float* tr_w1   = (const float*)d_in[39];
  const float* tr_b1   = (const float*)d_in[40];
  const float* tr_w2   = (const float*)d_in[41];
  const float* tr_b2   = (const float*)d_in[42];

  float* ws  = (float*)d_ws;
  float* rt  = ws;                    // 4096
  float* act = ws + 4096;             // 4 M floats
  float* xln = act + P64;             // 4 M
  float* nbT = xln + P64;             // 256 K
  float* b0  = nbT + 262144;          // 4 M
  float* b1  = b0 + P64;              // 4 M
  float* b2  = b1 + P64;              // 4 M
  float* b3  = (float*)d_out;         // gate / plane scratch; final output

  dim3 blk(256);

  k_transform<<<1, blk, 0, stream>>>(apos, rt);
  k_feat_embed<<<256, blk, 0, stream>>>(aatype, bmask, beta, amask, rt, emb_w, emb_b, act);

  for (int B = 0; B < 2; B++) {
    // ---- triangle attention (starting e=0, ending e=1) ----
    for (int e = 0; e < 2; e++) {
      int bi = B*2 + e;
      k_ln<<<2048, blk, 0, stream>>>(act, xln, ta_ln_s + bi*64, ta_ln_b + bi*64, e);
      k_nb<<<256, blk, 0, stream>>>(xln, ta_f2d + bi*256, nbT);
      k_proj<<<dim3(1024), blk, 0, stream>>>(
          xln, ta_qw + bi*4096, ta_kw + bi*4096, ta_vw + bi*4096, ta_gw + bi*4096,
          ta_gb + bi*64, b0, b1, b2, b3);
      k_attn<<<dim3(256, 4), dim3(128), 0, stream>>>(b0, b1, b2, b3, nbT, mask2d, e);
      if (e == 0)
        k_gemm<0,true,false><<<dim3(1024, 1), blk, 0, stream>>>(
            b0, 64, 64, ta_ow + bi*4096, ta_ob + bi*64, act);
      else
        k_gemm<0,true,true><<<dim3(1024, 1), blk, 0, stream>>>(
            b0, 64, 64, ta_ow + bi*4096, ta_ob + bi*64, act);
    }
    // ---- triangle multiplication (outgoing e=0, incoming e=1) ----
    for (int e = 0; e < 2; e++) {
      int bi = B*2 + e;
      k_ln<<<2048, blk, 0, stream>>>(act, xln, tm_ln_s + bi*64, tm_ln_b + bi*64, 0);
      k_dual2<<<dim3(1024, 2), blk, 0, stream>>>(
          xln, tm_lpw + bi*4096, tm_lpb + bi*64, tm_lgw + bi*4096, tm_lgb + bi*64,
          tm_rpw + bi*4096, tm_rpb + bi*64, tm_rgw + bi*4096, tm_rgb + bi*64,
          mask2d, b1, b2);
      if (e == 0)  // outgoing: NT on planes
        k_plane_gemm<false><<<dim3(64, 4, 4), blk, 0, stream>>>(b1, b2, b3);
      else         // incoming: TN on planes
        k_plane_gemm<true><<<dim3(64, 4, 4), blk, 0, stream>>>(b2, b1, b3);
      k_gate<<<1024, blk, 0, stream>>>(
          b3, xln, tm_cln_s + bi*64, tm_cln_b + bi*64,
          tm_ow + bi*4096, tm_ob + bi*64, tm_gw + bi*4096, tm_gb + bi*64, act);
    }
    // ---- transition ----
    k_ln<<<2048, blk, 0, stream>>>(act, xln, tr_ln_s + B*64, tr_ln_b + B*64, 0);
    k_gemm<2,false,false><<<dim3(1024, 2), blk, 0, stream>>>(
        xln, 64, 128, tr_w1 + B*8192, tr_b1 + B*128, b1);
    k_gemm<0,true,false><<<dim3(1024, 1), blk, 0, stream>>>(
        b1, 128, 64, tr_w2 + B*8192, tr_b2 + B*64, act);
  }

  k_ln<<<2048, blk, 0, stream>>>(act, (float*)d_out, out_ln_s, out_ln_b, 0);
}